// Round 1
// baseline (246.058 us; speedup 1.0000x reference)
//
#include <hip/hip_runtime.h>
#include <stdint.h>

// ---- types ----
typedef __bf16 bf16x8 __attribute__((ext_vector_type(8)));
typedef float  f32x4  __attribute__((ext_vector_type(4)));
typedef unsigned int u32x4 __attribute__((ext_vector_type(4)));
typedef unsigned short u16;

__device__ __forceinline__ u16 f2bf(float f) {
    union { float f; unsigned u; } v; v.f = f;
    unsigned r = v.u + 0x7fffu + ((v.u >> 16) & 1u);
    return (u16)(r >> 16);
}

// packed 2x f32 -> bf16 (RNE); [15:0]=a, [31:16]=b
__device__ __forceinline__ unsigned pk_bf16(float a, float b) {
#if __has_builtin(__builtin_amdgcn_cvt_pk_bf16_f32)
    typedef __bf16 bf16x2_t __attribute__((ext_vector_type(2)));
    bf16x2_t r = __builtin_amdgcn_cvt_pk_bf16_f32(a, b);
    return __builtin_bit_cast(unsigned, r);
#else
    return (unsigned)f2bf(a) | ((unsigned)f2bf(b) << 16);
#endif
}

__device__ __forceinline__ bf16x8 ld_frag(const u16* p) {
    u32x4 u = *(const u32x4*)p;
    return __builtin_bit_cast(bf16x8, u);
}

// async global->LDS, 16B per lane; LDS dest = wave-uniform base + lane*16
__device__ __forceinline__ void gload16(const u16* g, u16* l) {
    __builtin_amdgcn_global_load_lds(
        (__attribute__((address_space(1))) void*)g,
        (__attribute__((address_space(3))) void*)l,
        16, 0, 0);
}

#define ATT_CSC 0.18033688011112042f  // (1/sqrt(64)) * log2(e)

// ---- fused fp32 -> bf16 convert for all 4 arrays (float4-granular) ----
__global__ __launch_bounds__(256) void cvt_all(
    const float* __restrict__ x, const float* __restrict__ wg,
    const float* __restrict__ wqkv, const float* __restrict__ wproj,
    u16* __restrict__ xo, u16* __restrict__ wgo,
    u16* __restrict__ wqkvo, u16* __restrict__ wprojo)
{
    int i = blockIdx.x * 256 + threadIdx.x;   // grid covers exactly 2359296
    const float4* in; uint2* out; int off;
    if (i < 1048576)      { in = (const float4*)x;     out = (uint2*)xo;     off = i; }
    else if (i < 1310720) { in = (const float4*)wg;    out = (uint2*)wgo;    off = i - 1048576; }
    else if (i < 2097152) { in = (const float4*)wqkv;  out = (uint2*)wqkvo;  off = i - 1310720; }
    else                  { in = (const float4*)wproj; out = (uint2*)wprojo; off = i - 2097152; }
    float4 v = in[off];
    uint2 o; o.x = pk_bf16(v.x, v.y); o.y = pk_bf16(v.z, v.w);
    out[off] = o;
}

// ---- 128x128xBK32 bf16 MFMA GEMM (QKV), XOR-swizzled LDS ----
__global__ __launch_bounds__(256) void gemm_bt(
    const u16* __restrict__ A,      // [4096,1024]
    const u16* __restrict__ W,      // [3072,1024]
    const float* __restrict__ bias,
    u16* __restrict__ qo, u16* __restrict__ ko, u16* __restrict__ vTo)
{
    __shared__ alignas(16) u16 As[128 * 32];
    __shared__ alignas(16) u16 Bs[128 * 32];
    const int tid  = threadIdx.x;
    const int wave = tid >> 6, lane = tid & 63;
    const int lquad = lane >> 4, lcol = lane & 15;
    const int wr = (wave >> 1) * 64, wc = (wave & 1) * 64;
    const int rowb = blockIdx.x * 128, colb = blockIdx.y * 128;
    const int swc = (((lane & 3) ^ ((lane >> 2) & 3)) * 8);  // swizzled source chunk
    const int rsw = (lquad ^ (lcol & 3)) * 8;                // swizzled read chunk

    const u16* src  = (wave & 2) ? W : A;
    const int  rbase = (wave & 2) ? colb : rowb;
    u16* dst = ((wave & 2) ? Bs : As) + (wave & 1) * 64 * 32;
    const u16* gsrc = src + (size_t)(rbase + (wave & 1) * 64 + (lane >> 2)) * 1024 + swc;

    f32x4 zero4 = {0.f, 0.f, 0.f, 0.f};
    f32x4 acc[4][4];
#pragma unroll
    for (int i = 0; i < 4; i++)
#pragma unroll
        for (int j = 0; j < 4; j++) acc[i][j] = zero4;

    for (int k0 = 0; k0 < 1024; k0 += 32) {
        __syncthreads();
#pragma unroll
        for (int i = 0; i < 4; i++)
            gload16(gsrc + (size_t)(i * 16) * 1024 + k0, dst + i * 16 * 32);
        __syncthreads();
        bf16x8 af[4], bfr[4];
#pragma unroll
        for (int t = 0; t < 4; t++) af[t]  = ld_frag(As + (wr + t * 16 + lcol) * 32 + rsw);
#pragma unroll
        for (int t = 0; t < 4; t++) bfr[t] = ld_frag(Bs + (wc + t * 16 + lcol) * 32 + rsw);
#pragma unroll
        for (int i = 0; i < 4; i++)
#pragma unroll
            for (int j = 0; j < 4; j++)
                acc[i][j] = __builtin_amdgcn_mfma_f32_16x16x32_bf16(af[i], bfr[j], acc[i][j], 0, 0, 0);
    }

#pragma unroll
    for (int i = 0; i < 4; i++) {
#pragma unroll
        for (int j = 0; j < 4; j++) {
            int gcol = colb + wc + j * 16 + lcol;
            float bsv = bias[gcol];
            int grow0 = rowb + wr + i * 16 + lquad * 4;
            int three = gcol >> 10, rem = gcol & 1023;
            int h = rem >> 6, d = rem & 63;
            int b = grow0 >> 11, nn = grow0 & 2047;
            int bh = b * 16 + h;
            if (three == 2) {
                ushort4 o;
                o.x = f2bf(acc[i][j][0] + bsv);
                o.y = f2bf(acc[i][j][1] + bsv);
                o.z = f2bf(acc[i][j][2] + bsv);
                o.w = f2bf(acc[i][j][3] + bsv);
                *(ushort4*)(vTo + ((size_t)bh * 64 + d) * 2048 + nn) = o;
            } else if (three == 0) {
#pragma unroll
                for (int r = 0; r < 4; r++)
                    qo[((size_t)bh * 2048 + nn + r) * 64 + d] = f2bf((acc[i][j][r] + bsv) * ATT_CSC);
            } else {
#pragma unroll
                for (int r = 0; r < 4; r++)
                    ko[((size_t)bh * 2048 + nn + r) * 64 + d] = f2bf(acc[i][j][r] + bsv);
            }
        }
    }
}

// ---- 64x128xBK32 GEMM (gauge mode0 / proj mode2), grid (64, 8) = 512 blocks ----
__global__ __launch_bounds__(256) void gemm64(
    int mode,
    const u16* __restrict__ A,
    const u16* __restrict__ W,
    const float* __restrict__ bias,
    const float* __restrict__ xres,
    const float* __restrict__ theta,
    u16* __restrict__ out_bf,
    float* __restrict__ out_f)
{
    __shared__ alignas(16) u16 As[64 * 32];
    __shared__ alignas(16) u16 Bs[128 * 32];
    const int tid  = threadIdx.x;
    const int wave = tid >> 6, lane = tid & 63;
    const int lquad = lane >> 4, lcol = lane & 15;
    const int wr = (wave & 1) * 32, wc = (wave >> 1) * 64;
    const int rowb = blockIdx.x * 64, colb = blockIdx.y * 128;
    const int swc = (((lane & 3) ^ ((lane >> 2) & 3)) * 8);
    const int rsw = (lquad ^ (lcol & 3)) * 8;

    const u16* gp[3]; u16* lp[3];
#pragma unroll
    for (int t = 0; t < 3; t++) {
        int id = wave + t * 4;
        if (id < 4) {
            gp[t] = A + (size_t)(rowb + id * 16 + (lane >> 2)) * 1024 + swc;
            lp[t] = As + id * 512;
        } else {
            int g = id - 4;
            gp[t] = W + (size_t)(colb + g * 16 + (lane >> 2)) * 1024 + swc;
            lp[t] = Bs + g * 512;
        }
    }

    f32x4 zero4 = {0.f, 0.f, 0.f, 0.f};
    f32x4 acc[2][4];
#pragma unroll
    for (int i = 0; i < 2; i++)
#pragma unroll
        for (int j = 0; j < 4; j++) acc[i][j] = zero4;

    for (int k0 = 0; k0 < 1024; k0 += 32) {
        __syncthreads();
#pragma unroll
        for (int t = 0; t < 3; t++)
            gload16(gp[t] + k0, lp[t]);
        __syncthreads();
        bf16x8 af[2], bfr[4];
#pragma unroll
        for (int t = 0; t < 2; t++) af[t]  = ld_frag(As + (wr + t * 16 + lcol) * 32 + rsw);
#pragma unroll
        for (int t = 0; t < 4; t++) bfr[t] = ld_frag(Bs + (wc + t * 16 + lcol) * 32 + rsw);
#pragma unroll
        for (int i = 0; i < 2; i++)
#pragma unroll
            for (int j = 0; j < 4; j++)
                acc[i][j] = __builtin_amdgcn_mfma_f32_16x16x32_bf16(af[i], bfr[j], acc[i][j], 0, 0, 0);
    }

#pragma unroll
    for (int i = 0; i < 2; i++) {
#pragma unroll
        for (int j = 0; j < 4; j++) {
            int gcol = colb + wc + j * 16 + lcol;
            float bsv = bias[gcol];
            int grow0 = rowb + wr + i * 16 + lquad * 4;
            if (mode == 0) {
#pragma unroll
                for (int r = 0; r < 4; r++) {
                    size_t idx = (size_t)(grow0 + r) * 1024 + gcol;
                    float val = acc[i][j][r] + bsv;
                    out_bf[idx] = f2bf(xres[idx] + 0.1f * (val * theta[gcol]));
                }
            } else {
#pragma unroll
                for (int r = 0; r < 4; r++)
                    out_f[(size_t)(grow0 + r) * 1024 + gcol] = acc[i][j][r] + bsv;
            }
        }
    }
}

// ---- flash attention: j-tile 128 (two 64-j halves per barrier) ----
// S^T = K Q'^T (q pre-scaled), P = exp2(S^T), O^T = V^T P^T
// P stays fully in-register: cross-quad shfl_xor transpose feeds PV directly.
// block: 4 waves x 32 q-rows = 128 q-rows; grid (16, 32)
__global__ __launch_bounds__(256) void attn_kernel(
    const u16* __restrict__ q,   // [B*H, N, D] (pre-scaled by csc)
    const u16* __restrict__ k,   // [B*H, N, D]
    const u16* __restrict__ vT,  // [B*H, D, N]
    u16* __restrict__ attnout)   // [B, N, H*D]
{
    __shared__ alignas(16) u16 Ks[2 * 2 * 64 * 32];   // [jh][db][j][32]
    __shared__ alignas(16) u16 Vs[2 * 2 * 64 * 32];   // [jh][jb][d][32]

    const int tid  = threadIdx.x;
    const int wave = tid >> 6, lane = tid & 63;
    const int lquad = lane >> 4, lcol = lane & 15;
    const int bh   = blockIdx.y;
    const int row0 = blockIdx.x * 128 + wave * 32;
    const int rsw  = (lquad ^ (lcol & 3)) * 8;

    // Q as B-operand: n=lcol (q-row), k=d ; two q-halves of 16
    bf16x8 qf[2][2];
#pragma unroll
    for (int qh = 0; qh < 2; qh++)
#pragma unroll
        for (int db = 0; db < 2; db++)
            qf[qh][db] = ld_frag(q + ((size_t)bh * 2048 + row0 + qh * 16 + lcol) * 64 + db * 32 + lquad * 8);

    f32x4 zero4 = {0.f, 0.f, 0.f, 0.f};
    f32x4 lacc[2] = {zero4, zero4};
    f32x4 oacc[2][4];
#pragma unroll
    for (int qh = 0; qh < 2; qh++)
#pragma unroll
        for (int dt = 0; dt < 4; dt++) oacc[qh][dt] = zero4;

    // staging: wave 0,1 -> K halves (d-split); wave 2,3 -> V^T halves (j-split)
    const int sb = wave & 1;
    const int srow = lane >> 2;
    const int swc  = (((lane & 3) ^ (srow & 3)) * 8);
    const u16* gK = k  + ((size_t)bh * 2048 + srow) * 64 + sb * 32 + swc;
    const u16* gV = vT + ((size_t)bh * 64 + srow) * 2048 + sb * 32 + swc;
    u16* ldst = ((wave & 2) ? Vs : Ks) + sb * 64 * 32;

    for (int j0 = 0; j0 < 2048; j0 += 128) {
        __syncthreads();
        if ((wave & 2) == 0) {
#pragma unroll
            for (int jh = 0; jh < 2; jh++)
#pragma unroll
                for (int i = 0; i < 4; i++)
                    gload16(gK + (size_t)(j0 + jh * 64 + i * 16) * 64, ldst + jh * 4096 + i * 16 * 32);
        } else {
#pragma unroll
            for (int jh = 0; jh < 2; jh++)
#pragma unroll
                for (int i = 0; i < 4; i++)
                    gload16(gV + (size_t)(i * 16) * 2048 + j0 + jh * 64, ldst + jh * 4096 + i * 16 * 32);
        }
        __syncthreads();

#pragma unroll
        for (int jh = 0; jh < 2; jh++) {
            const u16* Ksb = Ks + jh * 4096;
            const u16* Vsb = Vs + jh * 4096;

            // S^T = K Q'^T : rows j (4 frags), col q = lcol; kf reused across q-halves
            f32x4 sacc[2][4];
#pragma unroll
            for (int qh = 0; qh < 2; qh++)
#pragma unroll
                for (int jt = 0; jt < 4; jt++) sacc[qh][jt] = zero4;
            __builtin_amdgcn_s_setprio(1);
#pragma unroll
            for (int jt = 0; jt < 4; jt++)
#pragma unroll
                for (int db = 0; db < 2; db++) {
                    bf16x8 kf = ld_frag(Ksb + db * 64 * 32 + (jt * 16 + lcol) * 32 + rsw);
#pragma unroll
                    for (int qh = 0; qh < 2; qh++)
                        sacc[qh][jt] = __builtin_amdgcn_mfma_f32_16x16x32_bf16(kf, qf[qh][db], sacc[qh][jt], 0, 0, 0);
                }
            __builtin_amdgcn_s_setprio(0);

            // fixed-max softmax: p = exp2(s); pack to bf16 pairs in-register
            // lane(g=lquad, c=lcol) holds P[j = jt*16 + 4g + r][q = c]
            unsigned dpk[2][4][2];
#pragma unroll
            for (int qh = 0; qh < 2; qh++) {
#pragma unroll
                for (int jt = 0; jt < 4; jt++) {
                    f32x4 pe;
                    pe[0] = __builtin_amdgcn_exp2f(sacc[qh][jt][0]);
                    pe[1] = __builtin_amdgcn_exp2f(sacc[qh][jt][1]);
                    pe[2] = __builtin_amdgcn_exp2f(sacc[qh][jt][2]);
                    pe[3] = __builtin_amdgcn_exp2f(sacc[qh][jt][3]);
                    lacc[qh] += pe;
                    dpk[qh][jt][0] = pk_bf16(pe[0], pe[1]);
                    dpk[qh][jt][1] = pk_bf16(pe[2], pe[3]);
                }
            }

            // in-register P transpose: PV B-operand needs P[j = kb*32 + 8g + e][q=c].
            // A_g = dpk[2kb]   (j = 32kb + 4g + {0..3})
            // B_g = dpk[2kb+1] (j = 32kb + 16 + 4g + {0..3})
            // target: g0 <- {A0,A1}, g1 <- {A2,A3}, g2 <- {B0,B1}, g3 <- {B2,B3}
            // step1 (lane^32 = quad^2): publish (g<2 ? B : A)
            // step2 (lane^16 = quad^1): publish (g==1 ? A : g==2 ? B : r1)
            bf16x8 pf[2][2];
#pragma unroll
            for (int qh = 0; qh < 2; qh++) {
#pragma unroll
                for (int kb = 0; kb < 2; kb++) {
                    unsigned Ax = dpk[qh][2 * kb][0],     Ay = dpk[qh][2 * kb][1];
                    unsigned Bx = dpk[qh][2 * kb + 1][0], By = dpk[qh][2 * kb + 1][1];
                    unsigned x1x = (lquad < 2) ? Bx : Ax;
                    unsigned x1y = (lquad < 2) ? By : Ay;
                    unsigned r1x = __shfl_xor(x1x, 32, 64);
                    unsigned r1y = __shfl_xor(x1y, 32, 64);
                    unsigned x2x = (lquad == 1) ? Ax : (lquad == 2) ? Bx : r1x;
                    unsigned x2y = (lquad == 1) ? Ay : (lquad == 2) ? By : r1y;
                    unsigned r2x = __shfl_xor(x2x, 16, 64);
                    unsigned r2y = __shfl_xor(x2y, 16, 64);
                    u32x4 w;
                    w[0] = (lquad == 0) ? Ax : (lquad == 2) ? r1x : r2x;
                    w[1] = (lquad == 0) ? Ay : (lquad == 2) ? r1y : r2y;
                    w[2] = (lquad == 1) ? r1x : (lquad == 3) ? Bx : r2x;
                    w[3] = (lquad == 1) ? r1y : (lquad == 3) ? By : r2y;
                    pf[qh][kb] = __builtin_bit_cast(bf16x8, w);
                }
            }

            // O^T += V^T P^T ; vf reused across q-halves
            __builtin_amdgcn_s_setprio(1);
#pragma unroll
            for (int dt = 0; dt < 4; dt++)
#pragma unroll
                for (int kb = 0; kb < 2; kb++) {
                    bf16x8 vf = ld_frag(Vsb + kb * 64 * 32 + (dt * 16 + lcol) * 32 + rsw);
#pragma unroll
                    for (int qh = 0; qh < 2; qh++)
                        oacc[qh][dt] = __builtin_amdgcn_mfma_f32_16x16x32_bf16(vf, pf[qh][kb], oacc[qh][dt], 0, 0, 0);
                }
            __builtin_amdgcn_s_setprio(0);
        }
    }

    // epilogue: O^T[d][q]/l -> attnout[b, n=q, h*64+d]
    const int b = bh >> 4, h = bh & 15;
#pragma unroll
    for (int qh = 0; qh < 2; qh++) {
        float l = (lacc[qh][0] + lacc[qh][1]) + (lacc[qh][2] + lacc[qh][3]);
        l += __shfl_xor(l, 16, 64);
        l += __shfl_xor(l, 32, 64);
        float inv = 1.0f / l;
        const int n = row0 + qh * 16 + lcol;
        size_t base = ((size_t)b * 2048 + n) * 1024 + h * 64;
#pragma unroll
        for (int dt = 0; dt < 4; dt++) {
            uint2 o;
            o.x = pk_bf16(oacc[qh][dt][0] * inv, oacc[qh][dt][1] * inv);
            o.y = pk_bf16(oacc[qh][dt][2] * inv, oacc[qh][dt][3] * inv);
            *(uint2*)(attnout + base + dt * 16 + lquad * 4) = o;
        }
    }
}

extern "C" void kernel_launch(void* const* d_in, const int* in_sizes, int n_in,
                              void* d_out, int out_size, void* d_ws, size_t ws_size,
                              hipStream_t stream) {
    const float* x     = (const float*)d_in[0];
    const float* theta = (const float*)d_in[1];
    const float* Wg    = (const float*)d_in[2];
    const float* bg    = (const float*)d_in[3];
    const float* Wqkv  = (const float*)d_in[4];
    const float* bqkv  = (const float*)d_in[5];
    const float* Wproj = (const float*)d_in[6];
    const float* bproj = (const float*)d_in[7];
    float* out = (float*)d_out;

    unsigned char* ws = (unsigned char*)d_ws;
    const size_t MB = 1ull << 20;
    u16* x_bf     = (u16*)(ws + 0);
    u16* Wg_bf    = (u16*)(ws + 8 * MB);
    u16* Wqkv_bf  = (u16*)(ws + 10 * MB);
    u16* Wproj_bf = (u16*)(ws + 16 * MB);
    u16* xg_bf    = (u16*)(ws + 18 * MB);
    u16* q_bf     = (u16*)(ws + 26 * MB);
    u16* k_bf     = (u16*)(ws + 34 * MB);
    u16* vT_bf    = (u16*)(ws + 42 * MB);
    u16* ao_bf    = (u16*)(ws + 50 * MB);

    dim3 blk(256);
    cvt_all<<<9216, blk, 0, stream>>>(x, Wg, Wqkv, Wproj,
                                      x_bf, Wg_bf, Wqkv_bf, Wproj_bf);

    gemm64<<<dim3(64, 8), blk, 0, stream>>>(0, x_bf, Wg_bf, bg,
                                            x, theta, xg_bf, nullptr);
    gemm_bt<<<dim3(32, 24), blk, 0, stream>>>(xg_bf, Wqkv_bf, bqkv,
                                              q_bf, k_bf, vT_bf);
    attn_kernel<<<dim3(16, 32), blk, 0, stream>>>(q_bf, k_bf, vT_bf, ao_bf);
    gemm64<<<dim3(64, 8), blk, 0, stream>>>(2, ao_bf, Wproj_bf, bproj,
                                            nullptr, nullptr, nullptr, out);
}

// Round 2
// 240.888 us; speedup vs baseline: 1.0215x; 1.0215x over previous
//
#include <hip/hip_runtime.h>
#include <stdint.h>

// ---- types ----
typedef __bf16 bf16x8 __attribute__((ext_vector_type(8)));
typedef float  f32x4  __attribute__((ext_vector_type(4)));
typedef unsigned int u32x4 __attribute__((ext_vector_type(4)));
typedef unsigned short u16;

__device__ __forceinline__ u16 f2bf(float f) {
    union { float f; unsigned u; } v; v.f = f;
    unsigned r = v.u + 0x7fffu + ((v.u >> 16) & 1u);
    return (u16)(r >> 16);
}

// packed 2x f32 -> bf16 (RNE); [15:0]=a, [31:16]=b
__device__ __forceinline__ unsigned pk_bf16(float a, float b) {
#if __has_builtin(__builtin_amdgcn_cvt_pk_bf16_f32)
    typedef __bf16 bf16x2_t __attribute__((ext_vector_type(2)));
    bf16x2_t r = __builtin_amdgcn_cvt_pk_bf16_f32(a, b);
    return __builtin_bit_cast(unsigned, r);
#else
    return (unsigned)f2bf(a) | ((unsigned)f2bf(b) << 16);
#endif
}

__device__ __forceinline__ bf16x8 ld_frag(const u16* p) {
    u32x4 u = *(const u32x4*)p;
    return __builtin_bit_cast(bf16x8, u);
}

// async global->LDS, 16B per lane; LDS dest = wave-uniform base + lane*16
__device__ __forceinline__ void gload16(const u16* g, u16* l) {
    __builtin_amdgcn_global_load_lds(
        (__attribute__((address_space(1))) void*)g,
        (__attribute__((address_space(3))) void*)l,
        16, 0, 0);
}

#define ATT_CSC 0.18033688011112042f  // (1/sqrt(64)) * log2(e)

// ---- fused fp32 -> bf16 convert for all 4 arrays (float4-granular) ----
__global__ __launch_bounds__(256) void cvt_all(
    const float* __restrict__ x, const float* __restrict__ wg,
    const float* __restrict__ wqkv, const float* __restrict__ wproj,
    u16* __restrict__ xo, u16* __restrict__ wgo,
    u16* __restrict__ wqkvo, u16* __restrict__ wprojo)
{
    int i = blockIdx.x * 256 + threadIdx.x;   // grid covers exactly 2359296
    const float4* in; uint2* out; int off;
    if (i < 1048576)      { in = (const float4*)x;     out = (uint2*)xo;     off = i; }
    else if (i < 1310720) { in = (const float4*)wg;    out = (uint2*)wgo;    off = i - 1048576; }
    else if (i < 2097152) { in = (const float4*)wqkv;  out = (uint2*)wqkvo;  off = i - 1310720; }
    else                  { in = (const float4*)wproj; out = (uint2*)wprojo; off = i - 2097152; }
    float4 v = in[off];
    uint2 o; o.x = pk_bf16(v.x, v.y); o.y = pk_bf16(v.z, v.w);
    out[off] = o;
}

// ---- 128x128xBK32 bf16 MFMA GEMM (QKV), XOR-swizzled LDS ----
__global__ __launch_bounds__(256) void gemm_bt(
    const u16* __restrict__ A,      // [4096,1024]
    const u16* __restrict__ W,      // [3072,1024]
    const float* __restrict__ bias,
    u16* __restrict__ qo, u16* __restrict__ ko, u16* __restrict__ vTo)
{
    __shared__ alignas(16) u16 As[128 * 32];
    __shared__ alignas(16) u16 Bs[128 * 32];
    const int tid  = threadIdx.x;
    const int wave = tid >> 6, lane = tid & 63;
    const int lquad = lane >> 4, lcol = lane & 15;
    const int wr = (wave >> 1) * 64, wc = (wave & 1) * 64;
    const int rowb = blockIdx.x * 128, colb = blockIdx.y * 128;
    const int swc = (((lane & 3) ^ ((lane >> 2) & 3)) * 8);  // swizzled source chunk
    const int rsw = (lquad ^ (lcol & 3)) * 8;                // swizzled read chunk

    const u16* src  = (wave & 2) ? W : A;
    const int  rbase = (wave & 2) ? colb : rowb;
    u16* dst = ((wave & 2) ? Bs : As) + (wave & 1) * 64 * 32;
    const u16* gsrc = src + (size_t)(rbase + (wave & 1) * 64 + (lane >> 2)) * 1024 + swc;

    f32x4 zero4 = {0.f, 0.f, 0.f, 0.f};
    f32x4 acc[4][4];
#pragma unroll
    for (int i = 0; i < 4; i++)
#pragma unroll
        for (int j = 0; j < 4; j++) acc[i][j] = zero4;

    for (int k0 = 0; k0 < 1024; k0 += 32) {
        __syncthreads();
#pragma unroll
        for (int i = 0; i < 4; i++)
            gload16(gsrc + (size_t)(i * 16) * 1024 + k0, dst + i * 16 * 32);
        __syncthreads();
        bf16x8 af[4], bfr[4];
#pragma unroll
        for (int t = 0; t < 4; t++) af[t]  = ld_frag(As + (wr + t * 16 + lcol) * 32 + rsw);
#pragma unroll
        for (int t = 0; t < 4; t++) bfr[t] = ld_frag(Bs + (wc + t * 16 + lcol) * 32 + rsw);
#pragma unroll
        for (int i = 0; i < 4; i++)
#pragma unroll
            for (int j = 0; j < 4; j++)
                acc[i][j] = __builtin_amdgcn_mfma_f32_16x16x32_bf16(af[i], bfr[j], acc[i][j], 0, 0, 0);
    }

#pragma unroll
    for (int i = 0; i < 4; i++) {
#pragma unroll
        for (int j = 0; j < 4; j++) {
            int gcol = colb + wc + j * 16 + lcol;
            float bsv = bias[gcol];
            int grow0 = rowb + wr + i * 16 + lquad * 4;
            int three = gcol >> 10, rem = gcol & 1023;
            int h = rem >> 6, d = rem & 63;
            int b = grow0 >> 11, nn = grow0 & 2047;
            int bh = b * 16 + h;
            if (three == 2) {
                ushort4 o;
                o.x = f2bf(acc[i][j][0] + bsv);
                o.y = f2bf(acc[i][j][1] + bsv);
                o.z = f2bf(acc[i][j][2] + bsv);
                o.w = f2bf(acc[i][j][3] + bsv);
                *(ushort4*)(vTo + ((size_t)bh * 64 + d) * 2048 + nn) = o;
            } else if (three == 0) {
#pragma unroll
                for (int r = 0; r < 4; r++)
                    qo[((size_t)bh * 2048 + nn + r) * 64 + d] = f2bf((acc[i][j][r] + bsv) * ATT_CSC);
            } else {
#pragma unroll
                for (int r = 0; r < 4; r++)
                    ko[((size_t)bh * 2048 + nn + r) * 64 + d] = f2bf(acc[i][j][r] + bsv);
            }
        }
    }
}

// ---- 64x128xBK32 GEMM (gauge mode0 / proj mode2), grid (64, 8) = 512 blocks ----
__global__ __launch_bounds__(256) void gemm64(
    int mode,
    const u16* __restrict__ A,
    const u16* __restrict__ W,
    const float* __restrict__ bias,
    const float* __restrict__ xres,
    const float* __restrict__ theta,
    u16* __restrict__ out_bf,
    float* __restrict__ out_f)
{
    __shared__ alignas(16) u16 As[64 * 32];
    __shared__ alignas(16) u16 Bs[128 * 32];
    const int tid  = threadIdx.x;
    const int wave = tid >> 6, lane = tid & 63;
    const int lquad = lane >> 4, lcol = lane & 15;
    const int wr = (wave & 1) * 32, wc = (wave >> 1) * 64;
    const int rowb = blockIdx.x * 64, colb = blockIdx.y * 128;
    const int swc = (((lane & 3) ^ ((lane >> 2) & 3)) * 8);
    const int rsw = (lquad ^ (lcol & 3)) * 8;

    const u16* gp[3]; u16* lp[3];
#pragma unroll
    for (int t = 0; t < 3; t++) {
        int id = wave + t * 4;
        if (id < 4) {
            gp[t] = A + (size_t)(rowb + id * 16 + (lane >> 2)) * 1024 + swc;
            lp[t] = As + id * 512;
        } else {
            int g = id - 4;
            gp[t] = W + (size_t)(colb + g * 16 + (lane >> 2)) * 1024 + swc;
            lp[t] = Bs + g * 512;
        }
    }

    f32x4 zero4 = {0.f, 0.f, 0.f, 0.f};
    f32x4 acc[2][4];
#pragma unroll
    for (int i = 0; i < 2; i++)
#pragma unroll
        for (int j = 0; j < 4; j++) acc[i][j] = zero4;

    for (int k0 = 0; k0 < 1024; k0 += 32) {
        __syncthreads();
#pragma unroll
        for (int t = 0; t < 3; t++)
            gload16(gp[t] + k0, lp[t]);
        __syncthreads();
        bf16x8 af[2], bfr[4];
#pragma unroll
        for (int t = 0; t < 2; t++) af[t]  = ld_frag(As + (wr + t * 16 + lcol) * 32 + rsw);
#pragma unroll
        for (int t = 0; t < 4; t++) bfr[t] = ld_frag(Bs + (wc + t * 16 + lcol) * 32 + rsw);
#pragma unroll
        for (int i = 0; i < 2; i++)
#pragma unroll
            for (int j = 0; j < 4; j++)
                acc[i][j] = __builtin_amdgcn_mfma_f32_16x16x32_bf16(af[i], bfr[j], acc[i][j], 0, 0, 0);
    }

#pragma unroll
    for (int i = 0; i < 2; i++) {
#pragma unroll
        for (int j = 0; j < 4; j++) {
            int gcol = colb + wc + j * 16 + lcol;
            float bsv = bias[gcol];
            int grow0 = rowb + wr + i * 16 + lquad * 4;
            if (mode == 0) {
#pragma unroll
                for (int r = 0; r < 4; r++) {
                    size_t idx = (size_t)(grow0 + r) * 1024 + gcol;
                    float val = acc[i][j][r] + bsv;
                    out_bf[idx] = f2bf(xres[idx] + 0.1f * (val * theta[gcol]));
                }
            } else {
#pragma unroll
                for (int r = 0; r < 4; r++)
                    out_f[(size_t)(grow0 + r) * 1024 + gcol] = acc[i][j][r] + bsv;
            }
        }
    }
}

// ---- flash attention: j-tile 128 (two 64-j halves per barrier) ----
// S^T = K Q'^T (q pre-scaled), P = exp2(S^T), O^T = V^T P^T
// P stays fully in-register: permlane32/16_swap transpose feeds PV directly.
// block: 4 waves x 32 q-rows = 128 q-rows; grid (16, 32)
__global__ __launch_bounds__(256) void attn_kernel(
    const u16* __restrict__ q,   // [B*H, N, D] (pre-scaled by csc)
    const u16* __restrict__ k,   // [B*H, N, D]
    const u16* __restrict__ vT,  // [B*H, D, N]
    u16* __restrict__ attnout)   // [B, N, H*D]
{
    __shared__ alignas(16) u16 Ks[2 * 2 * 64 * 32];   // [jh][db][j][32]
    __shared__ alignas(16) u16 Vs[2 * 2 * 64 * 32];   // [jh][jb][d][32]

    const int tid  = threadIdx.x;
    const int wave = tid >> 6, lane = tid & 63;
    const int lquad = lane >> 4, lcol = lane & 15;
    const int bh   = blockIdx.y;
    const int row0 = blockIdx.x * 128 + wave * 32;
    const int rsw  = (lquad ^ (lcol & 3)) * 8;

    // Q as B-operand: n=lcol (q-row), k=d ; two q-halves of 16
    bf16x8 qf[2][2];
#pragma unroll
    for (int qh = 0; qh < 2; qh++)
#pragma unroll
        for (int db = 0; db < 2; db++)
            qf[qh][db] = ld_frag(q + ((size_t)bh * 2048 + row0 + qh * 16 + lcol) * 64 + db * 32 + lquad * 8);

    f32x4 zero4 = {0.f, 0.f, 0.f, 0.f};
    f32x4 lacc[2] = {zero4, zero4};
    f32x4 oacc[2][4];
#pragma unroll
    for (int qh = 0; qh < 2; qh++)
#pragma unroll
        for (int dt = 0; dt < 4; dt++) oacc[qh][dt] = zero4;

    // staging: wave 0,1 -> K halves (d-split); wave 2,3 -> V^T halves (j-split)
    const int sb = wave & 1;
    const int srow = lane >> 2;
    const int swc  = (((lane & 3) ^ (srow & 3)) * 8);
    const u16* gK = k  + ((size_t)bh * 2048 + srow) * 64 + sb * 32 + swc;
    const u16* gV = vT + ((size_t)bh * 64 + srow) * 2048 + sb * 32 + swc;
    u16* ldst = ((wave & 2) ? Vs : Ks) + sb * 64 * 32;

    for (int j0 = 0; j0 < 2048; j0 += 128) {
        __syncthreads();
        if ((wave & 2) == 0) {
#pragma unroll
            for (int jh = 0; jh < 2; jh++)
#pragma unroll
                for (int i = 0; i < 4; i++)
                    gload16(gK + (size_t)(j0 + jh * 64 + i * 16) * 64, ldst + jh * 4096 + i * 16 * 32);
        } else {
#pragma unroll
            for (int jh = 0; jh < 2; jh++)
#pragma unroll
                for (int i = 0; i < 4; i++)
                    gload16(gV + (size_t)(i * 16) * 2048 + j0 + jh * 64, ldst + jh * 4096 + i * 16 * 32);
        }
        __syncthreads();

#pragma unroll
        for (int jh = 0; jh < 2; jh++) {
            const u16* Ksb = Ks + jh * 4096;
            const u16* Vsb = Vs + jh * 4096;

            // S^T = K Q'^T : rows j (4 frags), col q = lcol; kf reused across q-halves
            f32x4 sacc[2][4];
#pragma unroll
            for (int qh = 0; qh < 2; qh++)
#pragma unroll
                for (int jt = 0; jt < 4; jt++) sacc[qh][jt] = zero4;
            __builtin_amdgcn_s_setprio(1);
#pragma unroll
            for (int jt = 0; jt < 4; jt++)
#pragma unroll
                for (int db = 0; db < 2; db++) {
                    bf16x8 kf = ld_frag(Ksb + db * 64 * 32 + (jt * 16 + lcol) * 32 + rsw);
#pragma unroll
                    for (int qh = 0; qh < 2; qh++)
                        sacc[qh][jt] = __builtin_amdgcn_mfma_f32_16x16x32_bf16(kf, qf[qh][db], sacc[qh][jt], 0, 0, 0);
                }
            __builtin_amdgcn_s_setprio(0);

            // fixed-max softmax: p = exp2(s); pack to bf16 pairs in-register
            // lane(g=lquad, c=lcol) holds P[j = jt*16 + 4g + r][q = c]
            unsigned dpk[2][4][2];
#pragma unroll
            for (int qh = 0; qh < 2; qh++) {
#pragma unroll
                for (int jt = 0; jt < 4; jt++) {
                    f32x4 pe;
                    pe[0] = __builtin_amdgcn_exp2f(sacc[qh][jt][0]);
                    pe[1] = __builtin_amdgcn_exp2f(sacc[qh][jt][1]);
                    pe[2] = __builtin_amdgcn_exp2f(sacc[qh][jt][2]);
                    pe[3] = __builtin_amdgcn_exp2f(sacc[qh][jt][3]);
                    lacc[qh] += pe;
                    dpk[qh][jt][0] = pk_bf16(pe[0], pe[1]);
                    dpk[qh][jt][1] = pk_bf16(pe[2], pe[3]);
                }
            }

            // in-register P transpose: PV B-operand needs P[j = kb*32 + 8g + e][q=c].
            // Have (packed pairs): A = dpk[2kb]: A.x = pair(16*2kb+4g+0,+1), A.y = +2,+3
            //                      B = dpk[2kb+1]: same j + 16.
            // Target quad g: w0..w3 = pairs (8g+0,1) (8g+2,3) (8g+4,5) (8g+6,7) + 32kb.
            //   => w0/w2 from {A.x quads 2g,2g+1 ; B.x ...}, w1/w3 same with .y
            // permlane32_swap(a,b): a'[hi half] = b[lo half]; b'[lo half] = a[hi half]
            // permlane16_swap(x,y): x'[odd quads] = y[even quads]; y'[even] = x[odd]
            //   chain verified element-wise for all 16 (quad,word) positions.
            bf16x8 pf[2][2];
#pragma unroll
            for (int qh = 0; qh < 2; qh++) {
#pragma unroll
                for (int kb = 0; kb < 2; kb++) {
                    unsigned Ax = dpk[qh][2 * kb][0],     Ay = dpk[qh][2 * kb][1];
                    unsigned Bx = dpk[qh][2 * kb + 1][0], By = dpk[qh][2 * kb + 1][1];
                    u32x4 w;
#if __has_builtin(__builtin_amdgcn_permlane32_swap) && __has_builtin(__builtin_amdgcn_permlane16_swap)
                    {
                        auto s1 = __builtin_amdgcn_permlane32_swap(Ax, Bx, false, false);
                        auto s2 = __builtin_amdgcn_permlane16_swap(s1[0], s1[1], false, false);
                        w[0] = s2[0]; w[2] = s2[1];
                        auto s3 = __builtin_amdgcn_permlane32_swap(Ay, By, false, false);
                        auto s4 = __builtin_amdgcn_permlane16_swap(s3[0], s3[1], false, false);
                        w[1] = s4[0]; w[3] = s4[1];
                    }
#else
                    {
                        unsigned x1x = (lquad < 2) ? Bx : Ax;
                        unsigned x1y = (lquad < 2) ? By : Ay;
                        unsigned r1x = __shfl_xor(x1x, 32, 64);
                        unsigned r1y = __shfl_xor(x1y, 32, 64);
                        unsigned x2x = (lquad == 1) ? Ax : (lquad == 2) ? Bx : r1x;
                        unsigned x2y = (lquad == 1) ? Ay : (lquad == 2) ? By : r1y;
                        unsigned r2x = __shfl_xor(x2x, 16, 64);
                        unsigned r2y = __shfl_xor(x2y, 16, 64);
                        w[0] = (lquad == 0) ? Ax : (lquad == 2) ? r1x : r2x;
                        w[1] = (lquad == 0) ? Ay : (lquad == 2) ? r1y : r2y;
                        w[2] = (lquad == 1) ? r1x : (lquad == 3) ? Bx : r2x;
                        w[3] = (lquad == 1) ? r1y : (lquad == 3) ? By : r2y;
                    }
#endif
                    pf[qh][kb] = __builtin_bit_cast(bf16x8, w);
                }
            }

            // O^T += V^T P^T ; vf reused across q-halves
            __builtin_amdgcn_s_setprio(1);
#pragma unroll
            for (int dt = 0; dt < 4; dt++)
#pragma unroll
                for (int kb = 0; kb < 2; kb++) {
                    bf16x8 vf = ld_frag(Vsb + kb * 64 * 32 + (dt * 16 + lcol) * 32 + rsw);
#pragma unroll
                    for (int qh = 0; qh < 2; qh++)
                        oacc[qh][dt] = __builtin_amdgcn_mfma_f32_16x16x32_bf16(vf, pf[qh][kb], oacc[qh][dt], 0, 0, 0);
                }
            __builtin_amdgcn_s_setprio(0);
        }
    }

    // epilogue: O^T[d][q]/l -> attnout[b, n=q, h*64+d]
    const int b = bh >> 4, h = bh & 15;
#pragma unroll
    for (int qh = 0; qh < 2; qh++) {
        float l = (lacc[qh][0] + lacc[qh][1]) + (lacc[qh][2] + lacc[qh][3]);
        l += __shfl_xor(l, 16, 64);
        l += __shfl_xor(l, 32, 64);
        float inv = 1.0f / l;
        const int n = row0 + qh * 16 + lcol;
        size_t base = ((size_t)b * 2048 + n) * 1024 + h * 64;
#pragma unroll
        for (int dt = 0; dt < 4; dt++) {
            uint2 o;
            o.x = pk_bf16(oacc[qh][dt][0] * inv, oacc[qh][dt][1] * inv);
            o.y = pk_bf16(oacc[qh][dt][2] * inv, oacc[qh][dt][3] * inv);
            *(uint2*)(attnout + base + dt * 16 + lquad * 4) = o;
        }
    }
}

extern "C" void kernel_launch(void* const* d_in, const int* in_sizes, int n_in,
                              void* d_out, int out_size, void* d_ws, size_t ws_size,
                              hipStream_t stream) {
    const float* x     = (const float*)d_in[0];
    const float* theta = (const float*)d_in[1];
    const float* Wg    = (const float*)d_in[2];
    const float* bg    = (const float*)d_in[3];
    const float* Wqkv  = (const float*)d_in[4];
    const float* bqkv  = (const float*)d_in[5];
    const float* Wproj = (const float*)d_in[6];
    const float* bproj = (const float*)d_in[7];
    float* out = (float*)d_out;

    unsigned char* ws = (unsigned char*)d_ws;
    const size_t MB = 1ull << 20;
    u16* x_bf     = (u16*)(ws + 0);
    u16* Wg_bf    = (u16*)(ws + 8 * MB);
    u16* Wqkv_bf  = (u16*)(ws + 10 * MB);
    u16* Wproj_bf = (u16*)(ws + 16 * MB);
    u16* xg_bf    = (u16*)(ws + 18 * MB);
    u16* q_bf     = (u16*)(ws + 26 * MB);
    u16* k_bf     = (u16*)(ws + 34 * MB);
    u16* vT_bf    = (u16*)(ws + 42 * MB);
    u16* ao_bf    = (u16*)(ws + 50 * MB);

    dim3 blk(256);
    cvt_all<<<9216, blk, 0, stream>>>(x, Wg, Wqkv, Wproj,
                                      x_bf, Wg_bf, Wqkv_bf, Wproj_bf);

    gemm64<<<dim3(64, 8), blk, 0, stream>>>(0, x_bf, Wg_bf, bg,
                                            x, theta, xg_bf, nullptr);
    gemm_bt<<<dim3(32, 24), blk, 0, stream>>>(xg_bf, Wqkv_bf, bqkv,
                                              q_bf, k_bf, vT_bf);
    attn_kernel<<<dim3(16, 32), blk, 0, stream>>>(q_bf, k_bf, vT_bf, ao_bf);
    gemm64<<<dim3(64, 8), blk, 0, stream>>>(2, ao_bf, Wproj_bf, bproj,
                                            nullptr, nullptr, nullptr, out);
}

// Round 3
// 236.632 us; speedup vs baseline: 1.0398x; 1.0180x over previous
//
#include <hip/hip_runtime.h>
#include <stdint.h>

// ---- types ----
typedef __bf16 bf16x8 __attribute__((ext_vector_type(8)));
typedef float  f32x4  __attribute__((ext_vector_type(4)));
typedef unsigned int u32x4 __attribute__((ext_vector_type(4)));
typedef unsigned short u16;

__device__ __forceinline__ u16 f2bf(float f) {
    union { float f; unsigned u; } v; v.f = f;
    unsigned r = v.u + 0x7fffu + ((v.u >> 16) & 1u);
    return (u16)(r >> 16);
}

// packed 2x f32 -> bf16 (RNE); [15:0]=a, [31:16]=b
__device__ __forceinline__ unsigned pk_bf16(float a, float b) {
#if __has_builtin(__builtin_amdgcn_cvt_pk_bf16_f32)
    typedef __bf16 bf16x2_t __attribute__((ext_vector_type(2)));
    bf16x2_t r = __builtin_amdgcn_cvt_pk_bf16_f32(a, b);
    return __builtin_bit_cast(unsigned, r);
#else
    return (unsigned)f2bf(a) | ((unsigned)f2bf(b) << 16);
#endif
}

__device__ __forceinline__ bf16x8 ld_frag(const u16* p) {
    u32x4 u = *(const u32x4*)p;
    return __builtin_bit_cast(bf16x8, u);
}

// async global->LDS, 16B per lane; LDS dest = wave-uniform base + lane*16
__device__ __forceinline__ void gload16(const u16* g, u16* l) {
    __builtin_amdgcn_global_load_lds(
        (__attribute__((address_space(1))) void*)g,
        (__attribute__((address_space(3))) void*)l,
        16, 0, 0);
}

#define ATT_CSC 0.18033688011112042f  // (1/sqrt(64)) * log2(e)

// ---- fused fp32 -> bf16 convert for all 4 arrays (float4-granular) ----
__global__ __launch_bounds__(256) void cvt_all(
    const float* __restrict__ x, const float* __restrict__ wg,
    const float* __restrict__ wqkv, const float* __restrict__ wproj,
    u16* __restrict__ xo, u16* __restrict__ wgo,
    u16* __restrict__ wqkvo, u16* __restrict__ wprojo)
{
    int i = blockIdx.x * 256 + threadIdx.x;   // grid covers exactly 2359296
    const float4* in; uint2* out; int off;
    if (i < 1048576)      { in = (const float4*)x;     out = (uint2*)xo;     off = i; }
    else if (i < 1310720) { in = (const float4*)wg;    out = (uint2*)wgo;    off = i - 1048576; }
    else if (i < 2097152) { in = (const float4*)wqkv;  out = (uint2*)wqkvo;  off = i - 1310720; }
    else                  { in = (const float4*)wproj; out = (uint2*)wprojo; off = i - 2097152; }
    float4 v = in[off];
    uint2 o; o.x = pk_bf16(v.x, v.y); o.y = pk_bf16(v.z, v.w);
    out[off] = o;
}

// ---- 128x128xBK32 bf16 MFMA GEMM (QKV), XOR-swizzled LDS ----
__global__ __launch_bounds__(256) void gemm_bt(
    const u16* __restrict__ A,      // [4096,1024]
    const u16* __restrict__ W,      // [3072,1024]
    const float* __restrict__ bias,
    u16* __restrict__ qo, u16* __restrict__ ko, u16* __restrict__ vTo)
{
    __shared__ alignas(16) u16 As[128 * 32];
    __shared__ alignas(16) u16 Bs[128 * 32];
    const int tid  = threadIdx.x;
    const int wave = tid >> 6, lane = tid & 63;
    const int lquad = lane >> 4, lcol = lane & 15;
    const int wr = (wave >> 1) * 64, wc = (wave & 1) * 64;
    const int rowb = blockIdx.x * 128, colb = blockIdx.y * 128;
    const int swc = (((lane & 3) ^ ((lane >> 2) & 3)) * 8);  // swizzled source chunk
    const int rsw = (lquad ^ (lcol & 3)) * 8;                // swizzled read chunk

    const u16* src  = (wave & 2) ? W : A;
    const int  rbase = (wave & 2) ? colb : rowb;
    u16* dst = ((wave & 2) ? Bs : As) + (wave & 1) * 64 * 32;
    const u16* gsrc = src + (size_t)(rbase + (wave & 1) * 64 + (lane >> 2)) * 1024 + swc;

    f32x4 zero4 = {0.f, 0.f, 0.f, 0.f};
    f32x4 acc[4][4];
#pragma unroll
    for (int i = 0; i < 4; i++)
#pragma unroll
        for (int j = 0; j < 4; j++) acc[i][j] = zero4;

    for (int k0 = 0; k0 < 1024; k0 += 32) {
        __syncthreads();
#pragma unroll
        for (int i = 0; i < 4; i++)
            gload16(gsrc + (size_t)(i * 16) * 1024 + k0, dst + i * 16 * 32);
        __syncthreads();
        bf16x8 af[4], bfr[4];
#pragma unroll
        for (int t = 0; t < 4; t++) af[t]  = ld_frag(As + (wr + t * 16 + lcol) * 32 + rsw);
#pragma unroll
        for (int t = 0; t < 4; t++) bfr[t] = ld_frag(Bs + (wc + t * 16 + lcol) * 32 + rsw);
#pragma unroll
        for (int i = 0; i < 4; i++)
#pragma unroll
            for (int j = 0; j < 4; j++)
                acc[i][j] = __builtin_amdgcn_mfma_f32_16x16x32_bf16(af[i], bfr[j], acc[i][j], 0, 0, 0);
    }

#pragma unroll
    for (int i = 0; i < 4; i++) {
#pragma unroll
        for (int j = 0; j < 4; j++) {
            int gcol = colb + wc + j * 16 + lcol;
            float bsv = bias[gcol];
            int grow0 = rowb + wr + i * 16 + lquad * 4;
            int three = gcol >> 10, rem = gcol & 1023;
            int h = rem >> 6, d = rem & 63;
            int b = grow0 >> 11, nn = grow0 & 2047;
            int bh = b * 16 + h;
            if (three == 2) {
                ushort4 o;
                o.x = f2bf(acc[i][j][0] + bsv);
                o.y = f2bf(acc[i][j][1] + bsv);
                o.z = f2bf(acc[i][j][2] + bsv);
                o.w = f2bf(acc[i][j][3] + bsv);
                *(ushort4*)(vTo + ((size_t)bh * 64 + d) * 2048 + nn) = o;
            } else if (three == 0) {
#pragma unroll
                for (int r = 0; r < 4; r++)
                    qo[((size_t)bh * 2048 + nn + r) * 64 + d] = f2bf((acc[i][j][r] + bsv) * ATT_CSC);
            } else {
#pragma unroll
                for (int r = 0; r < 4; r++)
                    ko[((size_t)bh * 2048 + nn + r) * 64 + d] = f2bf(acc[i][j][r] + bsv);
            }
        }
    }
}

// ---- 64x128xBK32 GEMM (gauge mode0 / proj mode2), grid (64, 8) = 512 blocks ----
__global__ __launch_bounds__(256) void gemm64(
    int mode,
    const u16* __restrict__ A,
    const u16* __restrict__ W,
    const float* __restrict__ bias,
    const float* __restrict__ xres,
    const float* __restrict__ theta,
    u16* __restrict__ out_bf,
    float* __restrict__ out_f)
{
    __shared__ alignas(16) u16 As[64 * 32];
    __shared__ alignas(16) u16 Bs[128 * 32];
    const int tid  = threadIdx.x;
    const int wave = tid >> 6, lane = tid & 63;
    const int lquad = lane >> 4, lcol = lane & 15;
    const int wr = (wave & 1) * 32, wc = (wave >> 1) * 64;
    const int rowb = blockIdx.x * 64, colb = blockIdx.y * 128;
    const int swc = (((lane & 3) ^ ((lane >> 2) & 3)) * 8);
    const int rsw = (lquad ^ (lcol & 3)) * 8;

    const u16* gp[3]; u16* lp[3];
#pragma unroll
    for (int t = 0; t < 3; t++) {
        int id = wave + t * 4;
        if (id < 4) {
            gp[t] = A + (size_t)(rowb + id * 16 + (lane >> 2)) * 1024 + swc;
            lp[t] = As + id * 512;
        } else {
            int g = id - 4;
            gp[t] = W + (size_t)(colb + g * 16 + (lane >> 2)) * 1024 + swc;
            lp[t] = Bs + g * 512;
        }
    }

    f32x4 zero4 = {0.f, 0.f, 0.f, 0.f};
    f32x4 acc[2][4];
#pragma unroll
    for (int i = 0; i < 2; i++)
#pragma unroll
        for (int j = 0; j < 4; j++) acc[i][j] = zero4;

    for (int k0 = 0; k0 < 1024; k0 += 32) {
        __syncthreads();
#pragma unroll
        for (int t = 0; t < 3; t++)
            gload16(gp[t] + k0, lp[t]);
        __syncthreads();
        bf16x8 af[2], bfr[4];
#pragma unroll
        for (int t = 0; t < 2; t++) af[t]  = ld_frag(As + (wr + t * 16 + lcol) * 32 + rsw);
#pragma unroll
        for (int t = 0; t < 4; t++) bfr[t] = ld_frag(Bs + (wc + t * 16 + lcol) * 32 + rsw);
#pragma unroll
        for (int i = 0; i < 2; i++)
#pragma unroll
            for (int j = 0; j < 4; j++)
                acc[i][j] = __builtin_amdgcn_mfma_f32_16x16x32_bf16(af[i], bfr[j], acc[i][j], 0, 0, 0);
    }

#pragma unroll
    for (int i = 0; i < 2; i++) {
#pragma unroll
        for (int j = 0; j < 4; j++) {
            int gcol = colb + wc + j * 16 + lcol;
            float bsv = bias[gcol];
            int grow0 = rowb + wr + i * 16 + lquad * 4;
            if (mode == 0) {
#pragma unroll
                for (int r = 0; r < 4; r++) {
                    size_t idx = (size_t)(grow0 + r) * 1024 + gcol;
                    float val = acc[i][j][r] + bsv;
                    out_bf[idx] = f2bf(xres[idx] + 0.1f * (val * theta[gcol]));
                }
            } else {
#pragma unroll
                for (int r = 0; r < 4; r++)
                    out_f[(size_t)(grow0 + r) * 1024 + gcol] = acc[i][j][r] + bsv;
            }
        }
    }
}

// ---- flash attention: j-tile 128, double-buffered K/V with prefetch ----
// S^T = K Q'^T (q pre-scaled), P = exp2(S^T), O^T = V^T P^T
// P stays fully in-register (permlane32/16_swap transpose).
// Next j-tile's global_load_lds issued BEFORE current tile's compute, so the
// vmcnt(0) drain at the end-of-iter barrier lands after ~2.5k cycles of
// compute (T3-minimum 2-phase prefetch). LDS 64 KiB, 2 blocks/CU.
// block: 4 waves x 32 q-rows = 128 q-rows; grid (16, 32)
__global__ __launch_bounds__(256) void attn_kernel(
    const u16* __restrict__ q,   // [B*H, N, D] (pre-scaled by csc)
    const u16* __restrict__ k,   // [B*H, N, D]
    const u16* __restrict__ vT,  // [B*H, D, N]
    u16* __restrict__ attnout)   // [B, N, H*D]
{
    __shared__ alignas(16) u16 Ks[2][2 * 2 * 64 * 32];   // [buf][jh][db][j][32]
    __shared__ alignas(16) u16 Vs[2][2 * 2 * 64 * 32];   // [buf][jh][jb][d][32]

    const int tid  = threadIdx.x;
    const int wave = tid >> 6, lane = tid & 63;
    const int lquad = lane >> 4, lcol = lane & 15;
    const int bh   = blockIdx.y;
    const int row0 = blockIdx.x * 128 + wave * 32;
    const int rsw  = (lquad ^ (lcol & 3)) * 8;

    // Q as B-operand: n=lcol (q-row), k=d ; two q-halves of 16
    bf16x8 qf[2][2];
#pragma unroll
    for (int qh = 0; qh < 2; qh++)
#pragma unroll
        for (int db = 0; db < 2; db++)
            qf[qh][db] = ld_frag(q + ((size_t)bh * 2048 + row0 + qh * 16 + lcol) * 64 + db * 32 + lquad * 8);

    // staging: wave 0,1 -> K halves (d-split); wave 2,3 -> V^T halves (j-split)
    const int sb = wave & 1;
    const int srow = lane >> 2;
    const int swc  = (((lane & 3) ^ (srow & 3)) * 8);
    const u16* gK = k  + ((size_t)bh * 2048 + srow) * 64 + sb * 32 + swc;
    const u16* gV = vT + ((size_t)bh * 64 + srow) * 2048 + sb * 32 + swc;

    auto stage = [&](int j0, int buf) {
        u16* ldst = ((wave & 2) ? Vs[buf] : Ks[buf]) + sb * 64 * 32;
        if ((wave & 2) == 0) {
#pragma unroll
            for (int jh = 0; jh < 2; jh++)
#pragma unroll
                for (int i = 0; i < 4; i++)
                    gload16(gK + (size_t)(j0 + jh * 64 + i * 16) * 64, ldst + jh * 4096 + i * 16 * 32);
        } else {
#pragma unroll
            for (int jh = 0; jh < 2; jh++)
#pragma unroll
                for (int i = 0; i < 4; i++)
                    gload16(gV + (size_t)(i * 16) * 2048 + j0 + jh * 64, ldst + jh * 4096 + i * 16 * 32);
        }
    };

    f32x4 zero4 = {0.f, 0.f, 0.f, 0.f};
    f32x4 lacc[2] = {zero4, zero4};
    f32x4 oacc[2][4];
#pragma unroll
    for (int qh = 0; qh < 2; qh++)
#pragma unroll
        for (int dt = 0; dt < 4; dt++) oacc[qh][dt] = zero4;

    stage(0, 0);
    __syncthreads();   // compiler drains vmcnt(0) here: buf0 ready

    for (int it = 0; it < 16; ++it) {
        const int buf = it & 1;
        // prefetch next tile into buf^1 (its last readers finished at the
        // previous end-of-iter barrier)
        if (it < 15) stage((it + 1) * 128, buf ^ 1);

#pragma unroll
        for (int jh = 0; jh < 2; jh++) {
            const u16* Ksb = Ks[buf] + jh * 4096;
            const u16* Vsb = Vs[buf] + jh * 4096;

            // S^T = K Q'^T : rows j (4 frags), col q = lcol; kf reused across q-halves
            f32x4 sacc[2][4];
#pragma unroll
            for (int qh = 0; qh < 2; qh++)
#pragma unroll
                for (int jt = 0; jt < 4; jt++) sacc[qh][jt] = zero4;
            __builtin_amdgcn_s_setprio(1);
#pragma unroll
            for (int jt = 0; jt < 4; jt++)
#pragma unroll
                for (int db = 0; db < 2; db++) {
                    bf16x8 kf = ld_frag(Ksb + db * 64 * 32 + (jt * 16 + lcol) * 32 + rsw);
#pragma unroll
                    for (int qh = 0; qh < 2; qh++)
                        sacc[qh][jt] = __builtin_amdgcn_mfma_f32_16x16x32_bf16(kf, qf[qh][db], sacc[qh][jt], 0, 0, 0);
                }
            __builtin_amdgcn_s_setprio(0);

            // fixed-max softmax: p = exp2(s); pack to bf16 pairs in-register
            // lane(g=lquad, c=lcol) holds P[j = jt*16 + 4g + r][q = c]
            unsigned dpk[2][4][2];
#pragma unroll
            for (int qh = 0; qh < 2; qh++) {
#pragma unroll
                for (int jt = 0; jt < 4; jt++) {
                    f32x4 pe;
                    pe[0] = __builtin_amdgcn_exp2f(sacc[qh][jt][0]);
                    pe[1] = __builtin_amdgcn_exp2f(sacc[qh][jt][1]);
                    pe[2] = __builtin_amdgcn_exp2f(sacc[qh][jt][2]);
                    pe[3] = __builtin_amdgcn_exp2f(sacc[qh][jt][3]);
                    lacc[qh] += pe;
                    dpk[qh][jt][0] = pk_bf16(pe[0], pe[1]);
                    dpk[qh][jt][1] = pk_bf16(pe[2], pe[3]);
                }
            }

            // in-register P transpose: PV B-operand needs P[j = kb*32 + 8g + e][q=c].
            // permlane32_swap then permlane16_swap redistributes the packed
            // pairs exactly (verified element-wise for all 16 quad/word slots).
            bf16x8 pf[2][2];
#pragma unroll
            for (int qh = 0; qh < 2; qh++) {
#pragma unroll
                for (int kb = 0; kb < 2; kb++) {
                    unsigned Ax = dpk[qh][2 * kb][0],     Ay = dpk[qh][2 * kb][1];
                    unsigned Bx = dpk[qh][2 * kb + 1][0], By = dpk[qh][2 * kb + 1][1];
                    u32x4 w;
#if __has_builtin(__builtin_amdgcn_permlane32_swap) && __has_builtin(__builtin_amdgcn_permlane16_swap)
                    {
                        auto s1 = __builtin_amdgcn_permlane32_swap(Ax, Bx, false, false);
                        auto s2 = __builtin_amdgcn_permlane16_swap(s1[0], s1[1], false, false);
                        w[0] = s2[0]; w[2] = s2[1];
                        auto s3 = __builtin_amdgcn_permlane32_swap(Ay, By, false, false);
                        auto s4 = __builtin_amdgcn_permlane16_swap(s3[0], s3[1], false, false);
                        w[1] = s4[0]; w[3] = s4[1];
                    }
#else
                    {
                        unsigned x1x = (lquad < 2) ? Bx : Ax;
                        unsigned x1y = (lquad < 2) ? By : Ay;
                        unsigned r1x = __shfl_xor(x1x, 32, 64);
                        unsigned r1y = __shfl_xor(x1y, 32, 64);
                        unsigned x2x = (lquad == 1) ? Ax : (lquad == 2) ? Bx : r1x;
                        unsigned x2y = (lquad == 1) ? Ay : (lquad == 2) ? By : r1y;
                        unsigned r2x = __shfl_xor(x2x, 16, 64);
                        unsigned r2y = __shfl_xor(x2y, 16, 64);
                        w[0] = (lquad == 0) ? Ax : (lquad == 2) ? r1x : r2x;
                        w[1] = (lquad == 0) ? Ay : (lquad == 2) ? r1y : r2y;
                        w[2] = (lquad == 1) ? r1x : (lquad == 3) ? Bx : r2x;
                        w[3] = (lquad == 1) ? r1y : (lquad == 3) ? By : r2y;
                    }
#endif
                    pf[qh][kb] = __builtin_bit_cast(bf16x8, w);
                }
            }

            // O^T += V^T P^T ; vf reused across q-halves
            __builtin_amdgcn_s_setprio(1);
#pragma unroll
            for (int dt = 0; dt < 4; dt++)
#pragma unroll
                for (int kb = 0; kb < 2; kb++) {
                    bf16x8 vf = ld_frag(Vsb + kb * 64 * 32 + (dt * 16 + lcol) * 32 + rsw);
#pragma unroll
                    for (int qh = 0; qh < 2; qh++)
                        oacc[qh][dt] = __builtin_amdgcn_mfma_f32_16x16x32_bf16(vf, pf[qh][kb], oacc[qh][dt], 0, 0, 0);
                }
            __builtin_amdgcn_s_setprio(0);
        }

        // end-of-iter: compiler drains vmcnt (prefetch done) + all reads of
        // buf complete before next iter overwrites it
        __syncthreads();
    }

    // epilogue: O^T[d][q]/l -> attnout[b, n=q, h*64+d]
    const int b = bh >> 4, h = bh & 15;
#pragma unroll
    for (int qh = 0; qh < 2; qh++) {
        float l = (lacc[qh][0] + lacc[qh][1]) + (lacc[qh][2] + lacc[qh][3]);
        l += __shfl_xor(l, 16, 64);
        l += __shfl_xor(l, 32, 64);
        float inv = 1.0f / l;
        const int n = row0 + qh * 16 + lcol;
        size_t base = ((size_t)b * 2048 + n) * 1024 + h * 64;
#pragma unroll
        for (int dt = 0; dt < 4; dt++) {
            uint2 o;
            o.x = pk_bf16(oacc[qh][dt][0] * inv, oacc[qh][dt][1] * inv);
            o.y = pk_bf16(oacc[qh][dt][2] * inv, oacc[qh][dt][3] * inv);
            *(uint2*)(attnout + base + dt * 16 + lquad * 4) = o;
        }
    }
}

extern "C" void kernel_launch(void* const* d_in, const int* in_sizes, int n_in,
                              void* d_out, int out_size, void* d_ws, size_t ws_size,
                              hipStream_t stream) {
    const float* x     = (const float*)d_in[0];
    const float* theta = (const float*)d_in[1];
    const float* Wg    = (const float*)d_in[2];
    const float* bg    = (const float*)d_in[3];
    const float* Wqkv  = (const float*)d_in[4];
    const float* bqkv  = (const float*)d_in[5];
    const float* Wproj = (const float*)d_in[6];
    const float* bproj = (const float*)d_in[7];
    float* out = (float*)d_out;

    unsigned char* ws = (unsigned char*)d_ws;
    const size_t MB = 1ull << 20;
    u16* x_bf     = (u16*)(ws + 0);
    u16* Wg_bf    = (u16*)(ws + 8 * MB);
    u16* Wqkv_bf  = (u16*)(ws + 10 * MB);
    u16* Wproj_bf = (u16*)(ws + 16 * MB);
    u16* xg_bf    = (u16*)(ws + 18 * MB);
    u16* q_bf     = (u16*)(ws + 26 * MB);
    u16* k_bf     = (u16*)(ws + 34 * MB);
    u16* vT_bf    = (u16*)(ws + 42 * MB);
    u16* ao_bf    = (u16*)(ws + 50 * MB);

    dim3 blk(256);
    cvt_all<<<9216, blk, 0, stream>>>(x, Wg, Wqkv, Wproj,
                                      x_bf, Wg_bf, Wqkv_bf, Wproj_bf);

    gemm64<<<dim3(64, 8), blk, 0, stream>>>(0, x_bf, Wg_bf, bg,
                                            x, theta, xg_bf, nullptr);
    gemm_bt<<<dim3(32, 24), blk, 0, stream>>>(xg_bf, Wqkv_bf, bqkv,
                                              q_bf, k_bf, vT_bf);
    attn_kernel<<<dim3(16, 32), blk, 0, stream>>>(q_bf, k_bf, vT_bf, ao_bf);
    gemm64<<<dim3(64, 8), blk, 0, stream>>>(2, ao_bf, Wproj_bf, bproj,
                                            nullptr, nullptr, nullptr, out);
}

// Round 4
// 230.919 us; speedup vs baseline: 1.0656x; 1.0247x over previous
//
#include <hip/hip_runtime.h>
#include <stdint.h>

// ---- types ----
typedef __bf16 bf16x8 __attribute__((ext_vector_type(8)));
typedef float  f32x4  __attribute__((ext_vector_type(4)));
typedef unsigned int u32x4 __attribute__((ext_vector_type(4)));
typedef unsigned short u16;

__device__ __forceinline__ u16 f2bf(float f) {
    union { float f; unsigned u; } v; v.f = f;
    unsigned r = v.u + 0x7fffu + ((v.u >> 16) & 1u);
    return (u16)(r >> 16);
}

// packed 2x f32 -> bf16 (RNE); [15:0]=a, [31:16]=b
__device__ __forceinline__ unsigned pk_bf16(float a, float b) {
#if __has_builtin(__builtin_amdgcn_cvt_pk_bf16_f32)
    typedef __bf16 bf16x2_t __attribute__((ext_vector_type(2)));
    bf16x2_t r = __builtin_amdgcn_cvt_pk_bf16_f32(a, b);
    return __builtin_bit_cast(unsigned, r);
#else
    return (unsigned)f2bf(a) | ((unsigned)f2bf(b) << 16);
#endif
}

__device__ __forceinline__ bf16x8 ld_frag(const u16* p) {
    u32x4 u = *(const u32x4*)p;
    return __builtin_bit_cast(bf16x8, u);
}

// async global->LDS, 16B per lane; LDS dest = wave-uniform base + lane*16
__device__ __forceinline__ void gload16(const u16* g, u16* l) {
    __builtin_amdgcn_global_load_lds(
        (__attribute__((address_space(1))) void*)g,
        (__attribute__((address_space(3))) void*)l,
        16, 0, 0);
}

#define ATT_CSC 0.18033688011112042f  // (1/sqrt(64)) * log2(e)

// ---- fused fp32 -> bf16 convert for all 4 arrays (float4-granular) ----
__global__ __launch_bounds__(256) void cvt_all(
    const float* __restrict__ x, const float* __restrict__ wg,
    const float* __restrict__ wqkv, const float* __restrict__ wproj,
    u16* __restrict__ xo, u16* __restrict__ wgo,
    u16* __restrict__ wqkvo, u16* __restrict__ wprojo)
{
    int i = blockIdx.x * 256 + threadIdx.x;   // grid covers exactly 2359296
    const float4* in; uint2* out; int off;
    if (i < 1048576)      { in = (const float4*)x;     out = (uint2*)xo;     off = i; }
    else if (i < 1310720) { in = (const float4*)wg;    out = (uint2*)wgo;    off = i - 1048576; }
    else if (i < 2097152) { in = (const float4*)wqkv;  out = (uint2*)wqkvo;  off = i - 1310720; }
    else                  { in = (const float4*)wproj; out = (uint2*)wprojo; off = i - 2097152; }
    float4 v = in[off];
    uint2 o; o.x = pk_bf16(v.x, v.y); o.y = pk_bf16(v.z, v.w);
    out[off] = o;
}

// ---- 128x128xBK32 bf16 MFMA GEMM (QKV), XOR-swizzled LDS ----
__global__ __launch_bounds__(256) void gemm_bt(
    const u16* __restrict__ A,      // [4096,1024]
    const u16* __restrict__ W,      // [3072,1024]
    const float* __restrict__ bias,
    u16* __restrict__ qo, u16* __restrict__ ko, u16* __restrict__ vTo)
{
    __shared__ alignas(16) u16 As[128 * 32];
    __shared__ alignas(16) u16 Bs[128 * 32];
    const int tid  = threadIdx.x;
    const int wave = tid >> 6, lane = tid & 63;
    const int lquad = lane >> 4, lcol = lane & 15;
    const int wr = (wave >> 1) * 64, wc = (wave & 1) * 64;
    const int rowb = blockIdx.x * 128, colb = blockIdx.y * 128;
    const int swc = (((lane & 3) ^ ((lane >> 2) & 3)) * 8);  // swizzled source chunk
    const int rsw = (lquad ^ (lcol & 3)) * 8;                // swizzled read chunk

    const u16* src  = (wave & 2) ? W : A;
    const int  rbase = (wave & 2) ? colb : rowb;
    u16* dst = ((wave & 2) ? Bs : As) + (wave & 1) * 64 * 32;
    const u16* gsrc = src + (size_t)(rbase + (wave & 1) * 64 + (lane >> 2)) * 1024 + swc;

    f32x4 zero4 = {0.f, 0.f, 0.f, 0.f};
    f32x4 acc[4][4];
#pragma unroll
    for (int i = 0; i < 4; i++)
#pragma unroll
        for (int j = 0; j < 4; j++) acc[i][j] = zero4;

    for (int k0 = 0; k0 < 1024; k0 += 32) {
        __syncthreads();
#pragma unroll
        for (int i = 0; i < 4; i++)
            gload16(gsrc + (size_t)(i * 16) * 1024 + k0, dst + i * 16 * 32);
        __syncthreads();
        bf16x8 af[4], bfr[4];
#pragma unroll
        for (int t = 0; t < 4; t++) af[t]  = ld_frag(As + (wr + t * 16 + lcol) * 32 + rsw);
#pragma unroll
        for (int t = 0; t < 4; t++) bfr[t] = ld_frag(Bs + (wc + t * 16 + lcol) * 32 + rsw);
#pragma unroll
        for (int i = 0; i < 4; i++)
#pragma unroll
            for (int j = 0; j < 4; j++)
                acc[i][j] = __builtin_amdgcn_mfma_f32_16x16x32_bf16(af[i], bfr[j], acc[i][j], 0, 0, 0);
    }

#pragma unroll
    for (int i = 0; i < 4; i++) {
#pragma unroll
        for (int j = 0; j < 4; j++) {
            int gcol = colb + wc + j * 16 + lcol;
            float bsv = bias[gcol];
            int grow0 = rowb + wr + i * 16 + lquad * 4;
            int three = gcol >> 10, rem = gcol & 1023;
            int h = rem >> 6, d = rem & 63;
            int b = grow0 >> 11, nn = grow0 & 2047;
            int bh = b * 16 + h;
            if (three == 2) {
                ushort4 o;
                o.x = f2bf(acc[i][j][0] + bsv);
                o.y = f2bf(acc[i][j][1] + bsv);
                o.z = f2bf(acc[i][j][2] + bsv);
                o.w = f2bf(acc[i][j][3] + bsv);
                *(ushort4*)(vTo + ((size_t)bh * 64 + d) * 2048 + nn) = o;
            } else if (three == 0) {
#pragma unroll
                for (int r = 0; r < 4; r++)
                    qo[((size_t)bh * 2048 + nn + r) * 64 + d] = f2bf((acc[i][j][r] + bsv) * ATT_CSC);
            } else {
#pragma unroll
                for (int r = 0; r < 4; r++)
                    ko[((size_t)bh * 2048 + nn + r) * 64 + d] = f2bf(acc[i][j][r] + bsv);
            }
        }
    }
}

// ---- 64x128xBK32 GEMM (gauge mode0 / proj mode2), grid (64, 8) = 512 blocks ----
__global__ __launch_bounds__(256) void gemm64(
    int mode,
    const u16* __restrict__ A,
    const u16* __restrict__ W,
    const float* __restrict__ bias,
    const float* __restrict__ xres,
    const float* __restrict__ theta,
    u16* __restrict__ out_bf,
    float* __restrict__ out_f)
{
    __shared__ alignas(16) u16 As[64 * 32];
    __shared__ alignas(16) u16 Bs[128 * 32];
    const int tid  = threadIdx.x;
    const int wave = tid >> 6, lane = tid & 63;
    const int lquad = lane >> 4, lcol = lane & 15;
    const int wr = (wave & 1) * 32, wc = (wave >> 1) * 64;
    const int rowb = blockIdx.x * 64, colb = blockIdx.y * 128;
    const int swc = (((lane & 3) ^ ((lane >> 2) & 3)) * 8);
    const int rsw = (lquad ^ (lcol & 3)) * 8;

    const u16* gp[3]; u16* lp[3];
#pragma unroll
    for (int t = 0; t < 3; t++) {
        int id = wave + t * 4;
        if (id < 4) {
            gp[t] = A + (size_t)(rowb + id * 16 + (lane >> 2)) * 1024 + swc;
            lp[t] = As + id * 512;
        } else {
            int g = id - 4;
            gp[t] = W + (size_t)(colb + g * 16 + (lane >> 2)) * 1024 + swc;
            lp[t] = Bs + g * 512;
        }
    }

    f32x4 zero4 = {0.f, 0.f, 0.f, 0.f};
    f32x4 acc[2][4];
#pragma unroll
    for (int i = 0; i < 2; i++)
#pragma unroll
        for (int j = 0; j < 4; j++) acc[i][j] = zero4;

    for (int k0 = 0; k0 < 1024; k0 += 32) {
        __syncthreads();
#pragma unroll
        for (int t = 0; t < 3; t++)
            gload16(gp[t] + k0, lp[t]);
        __syncthreads();
        bf16x8 af[2], bfr[4];
#pragma unroll
        for (int t = 0; t < 2; t++) af[t]  = ld_frag(As + (wr + t * 16 + lcol) * 32 + rsw);
#pragma unroll
        for (int t = 0; t < 4; t++) bfr[t] = ld_frag(Bs + (wc + t * 16 + lcol) * 32 + rsw);
#pragma unroll
        for (int i = 0; i < 2; i++)
#pragma unroll
            for (int j = 0; j < 4; j++)
                acc[i][j] = __builtin_amdgcn_mfma_f32_16x16x32_bf16(af[i], bfr[j], acc[i][j], 0, 0, 0);
    }

#pragma unroll
    for (int i = 0; i < 2; i++) {
#pragma unroll
        for (int j = 0; j < 4; j++) {
            int gcol = colb + wc + j * 16 + lcol;
            float bsv = bias[gcol];
            int grow0 = rowb + wr + i * 16 + lquad * 4;
            if (mode == 0) {
#pragma unroll
                for (int r = 0; r < 4; r++) {
                    size_t idx = (size_t)(grow0 + r) * 1024 + gcol;
                    float val = acc[i][j][r] + bsv;
                    out_bf[idx] = f2bf(xres[idx] + 0.1f * (val * theta[gcol]));
                }
            } else {
#pragma unroll
                for (int r = 0; r < 4; r++)
                    out_f[(size_t)(grow0 + r) * 1024 + gcol] = acc[i][j][r] + bsv;
            }
        }
    }
}

// ---- flash attention: split-j, 8 waves (2 j-groups x 4 q-waves) ----
// S^T = K Q'^T (q pre-scaled), P = exp2(S^T), O^T = V^T P^T
// Fixed-max softmax => attention is a pure linear accumulation over j, so
// disjoint j-halves can be computed by separate wave groups and the partial
// (O, l) summed at the end (LDS combine). 512 threads = 8 waves:
// group g = wave>>2 owns j in [g*1024, g*1024+1024); wq = wave&3 owns 32 q-rows.
// 4096 waves total = 4 waves/SIMD (vs 2 before). j-tile 64, double-buffered:
// LDS = 2 groups x 2 bufs x (K 8KB + V 8KB) = 64 KiB. grid (16, 32).
__global__ __launch_bounds__(512, 4) void attn_kernel(
    const u16* __restrict__ q,   // [B*H, N, D] (pre-scaled by csc)
    const u16* __restrict__ k,   // [B*H, N, D]
    const u16* __restrict__ vT,  // [B*H, D, N]
    u16* __restrict__ attnout)   // [B, N, H*D]
{
    __shared__ alignas(16) u16 smem[32768];   // 64 KiB
    // Ks: smem          + g*8192 + buf*4096 + db*2048 : [db][j 64][32]
    // Vs: smem + 16384  + g*8192 + buf*4096 + jb*2048 : [jb][d 64][32]

    const int tid  = threadIdx.x;
    const int wave = tid >> 6, lane = tid & 63;
    const int g = wave >> 2, wq = wave & 3;
    const int lquad = lane >> 4, lcol = lane & 15;
    const int bh   = blockIdx.y;
    const int row0 = blockIdx.x * 128 + wq * 32;
    const int rsw  = (lquad ^ (lcol & 3)) * 8;

    u16* KsG = smem + g * 8192;
    u16* VsG = smem + 16384 + g * 8192;

    // Q as B-operand: n=lcol (q-row), k=d ; two q-halves of 16
    bf16x8 qf[2][2];
#pragma unroll
    for (int qh = 0; qh < 2; qh++)
#pragma unroll
        for (int db = 0; db < 2; db++)
            qf[qh][db] = ld_frag(q + ((size_t)bh * 2048 + row0 + qh * 16 + lcol) * 64 + db * 32 + lquad * 8);

    // staging roles within each group: wq 0,1 -> K (d-halves); wq 2,3 -> V^T (j-halves)
    const int sb = wq & 1;
    const int srow = lane >> 2;
    const int swc  = (((lane & 3) ^ (srow & 3)) * 8);
    const u16* gK = k  + ((size_t)bh * 2048 + srow) * 64 + sb * 32 + swc;
    const u16* gV = vT + ((size_t)bh * 64 + srow) * 2048 + sb * 32 + swc;

    auto stage = [&](int it, int buf) {
        int j0 = g * 1024 + it * 64;
        if ((wq & 2) == 0) {
            u16* ldst = KsG + buf * 4096 + sb * 2048;
#pragma unroll
            for (int i = 0; i < 4; i++)
                gload16(gK + (size_t)(j0 + i * 16) * 64, ldst + i * 16 * 32);
        } else {
            u16* ldst = VsG + buf * 4096 + sb * 2048;
#pragma unroll
            for (int i = 0; i < 4; i++)
                gload16(gV + (size_t)(i * 16) * 2048 + j0, ldst + i * 16 * 32);
        }
    };

    f32x4 zero4 = {0.f, 0.f, 0.f, 0.f};
    f32x4 lacc[2] = {zero4, zero4};
    f32x4 oacc[2][4];
#pragma unroll
    for (int qh = 0; qh < 2; qh++)
#pragma unroll
        for (int dt = 0; dt < 4; dt++) oacc[qh][dt] = zero4;

    stage(0, 0);
    __syncthreads();   // buf0 ready (vmcnt drained at barrier)

    for (int it = 0; it < 16; ++it) {
        const int buf = it & 1;
        // prefetch next tile into buf^1; its last readers finished at the
        // previous end-of-iter barrier
        if (it < 15) stage(it + 1, buf ^ 1);

        const u16* Kt = KsG + buf * 4096;
        const u16* Vt = VsG + buf * 4096;

        // S^T = K Q'^T : rows j (4 frags of 16), col q = lcol
        f32x4 sacc[2][4];
#pragma unroll
        for (int qh = 0; qh < 2; qh++)
#pragma unroll
            for (int jt = 0; jt < 4; jt++) sacc[qh][jt] = zero4;
        __builtin_amdgcn_s_setprio(1);
#pragma unroll
        for (int jt = 0; jt < 4; jt++)
#pragma unroll
            for (int db = 0; db < 2; db++) {
                bf16x8 kf = ld_frag(Kt + db * 2048 + (jt * 16 + lcol) * 32 + rsw);
#pragma unroll
                for (int qh = 0; qh < 2; qh++)
                    sacc[qh][jt] = __builtin_amdgcn_mfma_f32_16x16x32_bf16(kf, qf[qh][db], sacc[qh][jt], 0, 0, 0);
            }
        __builtin_amdgcn_s_setprio(0);

        // fixed-max softmax: p = exp2(s); pack to bf16 pairs in-register
        // lane(g=lquad, c=lcol) holds P[j = jt*16 + 4g + r][q = c]
        unsigned dpk[2][4][2];
#pragma unroll
        for (int qh = 0; qh < 2; qh++) {
#pragma unroll
            for (int jt = 0; jt < 4; jt++) {
                f32x4 pe;
                pe[0] = __builtin_amdgcn_exp2f(sacc[qh][jt][0]);
                pe[1] = __builtin_amdgcn_exp2f(sacc[qh][jt][1]);
                pe[2] = __builtin_amdgcn_exp2f(sacc[qh][jt][2]);
                pe[3] = __builtin_amdgcn_exp2f(sacc[qh][jt][3]);
                lacc[qh] += pe;
                dpk[qh][jt][0] = pk_bf16(pe[0], pe[1]);
                dpk[qh][jt][1] = pk_bf16(pe[2], pe[3]);
            }
        }

        // in-register P transpose: PV B-operand needs P[j = kb*32 + 8g + e][q=c].
        // permlane32_swap then permlane16_swap redistributes the packed pairs
        // exactly (verified element-wise for all 16 quad/word slots).
        bf16x8 pf[2][2];
#pragma unroll
        for (int qh = 0; qh < 2; qh++) {
#pragma unroll
            for (int kb = 0; kb < 2; kb++) {
                unsigned Ax = dpk[qh][2 * kb][0],     Ay = dpk[qh][2 * kb][1];
                unsigned Bx = dpk[qh][2 * kb + 1][0], By = dpk[qh][2 * kb + 1][1];
                u32x4 w;
#if __has_builtin(__builtin_amdgcn_permlane32_swap) && __has_builtin(__builtin_amdgcn_permlane16_swap)
                {
                    auto s1 = __builtin_amdgcn_permlane32_swap(Ax, Bx, false, false);
                    auto s2 = __builtin_amdgcn_permlane16_swap(s1[0], s1[1], false, false);
                    w[0] = s2[0]; w[2] = s2[1];
                    auto s3 = __builtin_amdgcn_permlane32_swap(Ay, By, false, false);
                    auto s4 = __builtin_amdgcn_permlane16_swap(s3[0], s3[1], false, false);
                    w[1] = s4[0]; w[3] = s4[1];
                }
#else
                {
                    unsigned x1x = (lquad < 2) ? Bx : Ax;
                    unsigned x1y = (lquad < 2) ? By : Ay;
                    unsigned r1x = __shfl_xor(x1x, 32, 64);
                    unsigned r1y = __shfl_xor(x1y, 32, 64);
                    unsigned x2x = (lquad == 1) ? Ax : (lquad == 2) ? Bx : r1x;
                    unsigned x2y = (lquad == 1) ? Ay : (lquad == 2) ? By : r1y;
                    unsigned r2x = __shfl_xor(x2x, 16, 64);
                    unsigned r2y = __shfl_xor(x2y, 16, 64);
                    w[0] = (lquad == 0) ? Ax : (lquad == 2) ? r1x : r2x;
                    w[1] = (lquad == 0) ? Ay : (lquad == 2) ? r1y : r2y;
                    w[2] = (lquad == 1) ? r1x : (lquad == 3) ? Bx : r2x;
                    w[3] = (lquad == 1) ? r1y : (lquad == 3) ? By : r2y;
                }
#endif
                pf[qh][kb] = __builtin_bit_cast(bf16x8, w);
            }
        }

        // O^T += V^T P^T ; vf reused across q-halves
        __builtin_amdgcn_s_setprio(1);
#pragma unroll
        for (int dt = 0; dt < 4; dt++)
#pragma unroll
            for (int kb = 0; kb < 2; kb++) {
                bf16x8 vf = ld_frag(Vt + kb * 2048 + (dt * 16 + lcol) * 32 + rsw);
#pragma unroll
                for (int qh = 0; qh < 2; qh++)
                    oacc[qh][dt] = __builtin_amdgcn_mfma_f32_16x16x32_bf16(vf, pf[qh][kb], oacc[qh][dt], 0, 0, 0);
            }
        __builtin_amdgcn_s_setprio(0);

        // end-of-iter: drains prefetch vmcnt + all reads of buf before reuse
        __syncthreads();
    }

    // ---- cross-group combine: g1 writes partial (O, l); g0 sums ----
    // slot stride 44 floats (176B, 16B-aligned; banks spread 12*l mod 32)
    float* scr = (float*)smem;
    const int slot = wq * 64 + lane;
    if (g == 1) {
#pragma unroll
        for (int qh = 0; qh < 2; qh++) {
#pragma unroll
            for (int dt = 0; dt < 4; dt++)
                *(f32x4*)&scr[slot * 44 + qh * 16 + dt * 4] = oacc[qh][dt];
            *(f32x4*)&scr[slot * 44 + 32 + qh * 4] = lacc[qh];
        }
    }
    __syncthreads();
    if (g == 1) return;

#pragma unroll
    for (int qh = 0; qh < 2; qh++) {
#pragma unroll
        for (int dt = 0; dt < 4; dt++)
            oacc[qh][dt] += *(const f32x4*)&scr[slot * 44 + qh * 16 + dt * 4];
        lacc[qh] += *(const f32x4*)&scr[slot * 44 + 32 + qh * 4];
    }

    // epilogue: O^T[d][q]/l -> attnout[b, n=q, h*64+d]
    const int b = bh >> 4, h = bh & 15;
#pragma unroll
    for (int qh = 0; qh < 2; qh++) {
        float l = (lacc[qh][0] + lacc[qh][1]) + (lacc[qh][2] + lacc[qh][3]);
        l += __shfl_xor(l, 16, 64);
        l += __shfl_xor(l, 32, 64);
        float inv = 1.0f / l;
        const int n = row0 + qh * 16 + lcol;
        size_t base = ((size_t)b * 2048 + n) * 1024 + h * 64;
#pragma unroll
        for (int dt = 0; dt < 4; dt++) {
            uint2 o;
            o.x = pk_bf16(oacc[qh][dt][0] * inv, oacc[qh][dt][1] * inv);
            o.y = pk_bf16(oacc[qh][dt][2] * inv, oacc[qh][dt][3] * inv);
            *(uint2*)(attnout + base + dt * 16 + lquad * 4) = o;
        }
    }
}

extern "C" void kernel_launch(void* const* d_in, const int* in_sizes, int n_in,
                              void* d_out, int out_size, void* d_ws, size_t ws_size,
                              hipStream_t stream) {
    const float* x     = (const float*)d_in[0];
    const float* theta = (const float*)d_in[1];
    const float* Wg    = (const float*)d_in[2];
    const float* bg    = (const float*)d_in[3];
    const float* Wqkv  = (const float*)d_in[4];
    const float* bqkv  = (const float*)d_in[5];
    const float* Wproj = (const float*)d_in[6];
    const float* bproj = (const float*)d_in[7];
    float* out = (float*)d_out;

    unsigned char* ws = (unsigned char*)d_ws;
    const size_t MB = 1ull << 20;
    u16* x_bf     = (u16*)(ws + 0);
    u16* Wg_bf    = (u16*)(ws + 8 * MB);
    u16* Wqkv_bf  = (u16*)(ws + 10 * MB);
    u16* Wproj_bf = (u16*)(ws + 16 * MB);
    u16* xg_bf    = (u16*)(ws + 18 * MB);
    u16* q_bf     = (u16*)(ws + 26 * MB);
    u16* k_bf     = (u16*)(ws + 34 * MB);
    u16* vT_bf    = (u16*)(ws + 42 * MB);
    u16* ao_bf    = (u16*)(ws + 50 * MB);

    dim3 blk(256);
    cvt_all<<<9216, blk, 0, stream>>>(x, Wg, Wqkv, Wproj,
                                      x_bf, Wg_bf, Wqkv_bf, Wproj_bf);

    gemm64<<<dim3(64, 8), blk, 0, stream>>>(0, x_bf, Wg_bf, bg,
                                            x, theta, xg_bf, nullptr);
    gemm_bt<<<dim3(32, 24), blk, 0, stream>>>(xg_bf, Wqkv_bf, bqkv,
                                              q_bf, k_bf, vT_bf);
    attn_kernel<<<dim3(16, 32), dim3(512), 0, stream>>>(q_bf, k_bf, vT_bf, ao_bf);
    gemm64<<<dim3(64, 8), blk, 0, stream>>>(2, ao_bf, Wproj_bf, bproj,
                                            nullptr, nullptr, nullptr, out);
}

// Round 5
// 208.486 us; speedup vs baseline: 1.1802x; 1.1076x over previous
//
#include <hip/hip_runtime.h>
#include <stdint.h>

// ---- types ----
typedef __bf16 bf16x8 __attribute__((ext_vector_type(8)));
typedef __bf16 bf16x2 __attribute__((ext_vector_type(2)));
typedef float  f32x4  __attribute__((ext_vector_type(4)));
typedef unsigned int u32x4 __attribute__((ext_vector_type(4)));
typedef unsigned short u16;

// native RNE cast; compiler emits v_cvt_pk_bf16_f32 for pairs (m240: scalar
// cast beats both hand-rolled bit-twiddle and inline-asm cvt_pk)
__device__ __forceinline__ u16 f2bf(float f) {
    return __builtin_bit_cast(u16, (__bf16)f);
}

// packed 2x f32 -> bf16 (RNE); [15:0]=a, [31:16]=b
__device__ __forceinline__ unsigned pk_bf16(float a, float b) {
    bf16x2 r; r[0] = (__bf16)a; r[1] = (__bf16)b;
    return __builtin_bit_cast(unsigned, r);
}

__device__ __forceinline__ bf16x8 ld_frag(const u16* p) {
    u32x4 u = *(const u32x4*)p;
    return __builtin_bit_cast(bf16x8, u);
}

// async global->LDS, 16B per lane; LDS dest = wave-uniform base + lane*16
__device__ __forceinline__ void gload16(const u16* g, u16* l) {
    __builtin_amdgcn_global_load_lds(
        (__attribute__((address_space(1))) void*)g,
        (__attribute__((address_space(3))) void*)l,
        16, 0, 0);
}

#define ATT_CSC 0.18033688011112042f  // (1/sqrt(64)) * log2(e)

// ---- fused fp32 -> bf16 convert for all 4 arrays (float4-granular) ----
__global__ __launch_bounds__(256) void cvt_all(
    const float* __restrict__ x, const float* __restrict__ wg,
    const float* __restrict__ wqkv, const float* __restrict__ wproj,
    u16* __restrict__ xo, u16* __restrict__ wgo,
    u16* __restrict__ wqkvo, u16* __restrict__ wprojo)
{
    int i = blockIdx.x * 256 + threadIdx.x;   // grid covers exactly 2359296
    const float4* in; uint2* out; int off;
    if (i < 1048576)      { in = (const float4*)x;     out = (uint2*)xo;     off = i; }
    else if (i < 1310720) { in = (const float4*)wg;    out = (uint2*)wgo;    off = i - 1048576; }
    else if (i < 2097152) { in = (const float4*)wqkv;  out = (uint2*)wqkvo;  off = i - 1310720; }
    else                  { in = (const float4*)wproj; out = (uint2*)wprojo; off = i - 2097152; }
    float4 v = in[off];
    uint2 o; o.x = pk_bf16(v.x, v.y); o.y = pk_bf16(v.z, v.w);
    out[off] = o;
}

// ---- 128x128xBK32 bf16 MFMA GEMM (QKV), XOR-swizzled LDS ----
__global__ __launch_bounds__(256) void gemm_bt(
    const u16* __restrict__ A,      // [4096,1024]
    const u16* __restrict__ W,      // [3072,1024]
    const float* __restrict__ bias,
    u16* __restrict__ qo, u16* __restrict__ ko, u16* __restrict__ vTo)
{
    __shared__ alignas(16) u16 As[128 * 32];
    __shared__ alignas(16) u16 Bs[128 * 32];
    const int tid  = threadIdx.x;
    const int wave = tid >> 6, lane = tid & 63;
    const int lquad = lane >> 4, lcol = lane & 15;
    const int wr = (wave >> 1) * 64, wc = (wave & 1) * 64;
    const int rowb = blockIdx.x * 128, colb = blockIdx.y * 128;
    const int swc = (((lane & 3) ^ ((lane >> 2) & 3)) * 8);  // swizzled source chunk
    const int rsw = (lquad ^ (lcol & 3)) * 8;                // swizzled read chunk

    const u16* src  = (wave & 2) ? W : A;
    const int  rbase = (wave & 2) ? colb : rowb;
    u16* dst = ((wave & 2) ? Bs : As) + (wave & 1) * 64 * 32;
    const u16* gsrc = src + (size_t)(rbase + (wave & 1) * 64 + (lane >> 2)) * 1024 + swc;

    f32x4 zero4 = {0.f, 0.f, 0.f, 0.f};
    f32x4 acc[4][4];
#pragma unroll
    for (int i = 0; i < 4; i++)
#pragma unroll
        for (int j = 0; j < 4; j++) acc[i][j] = zero4;

    for (int k0 = 0; k0 < 1024; k0 += 32) {
        __syncthreads();
#pragma unroll
        for (int i = 0; i < 4; i++)
            gload16(gsrc + (size_t)(i * 16) * 1024 + k0, dst + i * 16 * 32);
        __syncthreads();
        bf16x8 af[4], bfr[4];
#pragma unroll
        for (int t = 0; t < 4; t++) af[t]  = ld_frag(As + (wr + t * 16 + lcol) * 32 + rsw);
#pragma unroll
        for (int t = 0; t < 4; t++) bfr[t] = ld_frag(Bs + (wc + t * 16 + lcol) * 32 + rsw);
#pragma unroll
        for (int i = 0; i < 4; i++)
#pragma unroll
            for (int j = 0; j < 4; j++)
                acc[i][j] = __builtin_amdgcn_mfma_f32_16x16x32_bf16(af[i], bfr[j], acc[i][j], 0, 0, 0);
    }

#pragma unroll
    for (int i = 0; i < 4; i++) {
#pragma unroll
        for (int j = 0; j < 4; j++) {
            int gcol = colb + wc + j * 16 + lcol;
            float bsv = bias[gcol];
            int grow0 = rowb + wr + i * 16 + lquad * 4;
            int three = gcol >> 10, rem = gcol & 1023;
            int h = rem >> 6, d = rem & 63;
            int b = grow0 >> 11, nn = grow0 & 2047;
            int bh = b * 16 + h;
            if (three == 2) {
                ushort4 o;
                o.x = f2bf(acc[i][j][0] + bsv);
                o.y = f2bf(acc[i][j][1] + bsv);
                o.z = f2bf(acc[i][j][2] + bsv);
                o.w = f2bf(acc[i][j][3] + bsv);
                *(ushort4*)(vTo + ((size_t)bh * 64 + d) * 2048 + nn) = o;
            } else if (three == 0) {
#pragma unroll
                for (int r = 0; r < 4; r++)
                    qo[((size_t)bh * 2048 + nn + r) * 64 + d] = f2bf((acc[i][j][r] + bsv) * ATT_CSC);
            } else {
#pragma unroll
                for (int r = 0; r < 4; r++)
                    ko[((size_t)bh * 2048 + nn + r) * 64 + d] = f2bf(acc[i][j][r] + bsv);
            }
        }
    }
}

// ---- 64x128xBK32 GEMM (gauge mode0 / proj mode2), grid (64, 8) = 512 blocks ----
__global__ __launch_bounds__(256) void gemm64(
    int mode,
    const u16* __restrict__ A,
    const u16* __restrict__ W,
    const float* __restrict__ bias,
    const float* __restrict__ xres,
    const float* __restrict__ theta,
    u16* __restrict__ out_bf,
    float* __restrict__ out_f)
{
    __shared__ alignas(16) u16 As[64 * 32];
    __shared__ alignas(16) u16 Bs[128 * 32];
    const int tid  = threadIdx.x;
    const int wave = tid >> 6, lane = tid & 63;
    const int lquad = lane >> 4, lcol = lane & 15;
    const int wr = (wave & 1) * 32, wc = (wave >> 1) * 64;
    const int rowb = blockIdx.x * 64, colb = blockIdx.y * 128;
    const int swc = (((lane & 3) ^ ((lane >> 2) & 3)) * 8);
    const int rsw = (lquad ^ (lcol & 3)) * 8;

    const u16* gp[3]; u16* lp[3];
#pragma unroll
    for (int t = 0; t < 3; t++) {
        int id = wave + t * 4;
        if (id < 4) {
            gp[t] = A + (size_t)(rowb + id * 16 + (lane >> 2)) * 1024 + swc;
            lp[t] = As + id * 512;
        } else {
            int g = id - 4;
            gp[t] = W + (size_t)(colb + g * 16 + (lane >> 2)) * 1024 + swc;
            lp[t] = Bs + g * 512;
        }
    }

    f32x4 zero4 = {0.f, 0.f, 0.f, 0.f};
    f32x4 acc[2][4];
#pragma unroll
    for (int i = 0; i < 2; i++)
#pragma unroll
        for (int j = 0; j < 4; j++) acc[i][j] = zero4;

    for (int k0 = 0; k0 < 1024; k0 += 32) {
        __syncthreads();
#pragma unroll
        for (int t = 0; t < 3; t++)
            gload16(gp[t] + k0, lp[t]);
        __syncthreads();
        bf16x8 af[2], bfr[4];
#pragma unroll
        for (int t = 0; t < 2; t++) af[t]  = ld_frag(As + (wr + t * 16 + lcol) * 32 + rsw);
#pragma unroll
        for (int t = 0; t < 4; t++) bfr[t] = ld_frag(Bs + (wc + t * 16 + lcol) * 32 + rsw);
#pragma unroll
        for (int i = 0; i < 2; i++)
#pragma unroll
            for (int j = 0; j < 4; j++)
                acc[i][j] = __builtin_amdgcn_mfma_f32_16x16x32_bf16(af[i], bfr[j], acc[i][j], 0, 0, 0);
    }

#pragma unroll
    for (int i = 0; i < 2; i++) {
#pragma unroll
        for (int j = 0; j < 4; j++) {
            int gcol = colb + wc + j * 16 + lcol;
            float bsv = bias[gcol];
            int grow0 = rowb + wr + i * 16 + lquad * 4;
            if (mode == 0) {
#pragma unroll
                for (int r = 0; r < 4; r++) {
                    size_t idx = (size_t)(grow0 + r) * 1024 + gcol;
                    float val = acc[i][j][r] + bsv;
                    out_bf[idx] = f2bf(xres[idx] + 0.1f * (val * theta[gcol]));
                }
            } else {
#pragma unroll
                for (int r = 0; r < 4; r++)
                    out_f[(size_t)(grow0 + r) * 1024 + gcol] = acc[i][j][r] + bsv;
            }
        }
    }
}

// ---- flash attention: split-j, 8 waves (2 j-groups x 4 q-waves) ----
// S^T = K Q'^T (q pre-scaled), P = exp2(S^T), O^T = V^T P^T
// Fixed-max softmax => attention is a pure linear accumulation over j, so
// disjoint j-halves can be computed by separate wave groups and the partial
// (O, l) summed at the end (LDS combine). 512 threads = 8 waves:
// group g = wave>>2 owns j in [g*1024, g*1024+1024); wq = wave&3 owns 32 q-rows.
// 4 waves/SIMD. j-tile 64, double-buffered: LDS 64 KiB. grid (16, 32).
__global__ __launch_bounds__(512, 4) void attn_kernel(
    const u16* __restrict__ q,   // [B*H, N, D] (pre-scaled by csc)
    const u16* __restrict__ k,   // [B*H, N, D]
    const u16* __restrict__ vT,  // [B*H, D, N]
    u16* __restrict__ attnout)   // [B, N, H*D]
{
    __shared__ alignas(16) u16 smem[32768];   // 64 KiB
    // Ks: smem          + g*8192 + buf*4096 + db*2048 : [db][j 64][32]
    // Vs: smem + 16384  + g*8192 + buf*4096 + jb*2048 : [jb][d 64][32]

    const int tid  = threadIdx.x;
    const int wave = tid >> 6, lane = tid & 63;
    const int g = wave >> 2, wq = wave & 3;
    const int lquad = lane >> 4, lcol = lane & 15;
    const int bh   = blockIdx.y;
    const int row0 = blockIdx.x * 128 + wq * 32;
    const int rsw  = (lquad ^ (lcol & 3)) * 8;

    u16* KsG = smem + g * 8192;
    u16* VsG = smem + 16384 + g * 8192;

    // Q as B-operand: n=lcol (q-row), k=d ; two q-halves of 16
    bf16x8 qf[2][2];
#pragma unroll
    for (int qh = 0; qh < 2; qh++)
#pragma unroll
        for (int db = 0; db < 2; db++)
            qf[qh][db] = ld_frag(q + ((size_t)bh * 2048 + row0 + qh * 16 + lcol) * 64 + db * 32 + lquad * 8);

    // staging roles within each group: wq 0,1 -> K (d-halves); wq 2,3 -> V^T (j-halves)
    const int sb = wq & 1;
    const int srow = lane >> 2;
    const int swc  = (((lane & 3) ^ (srow & 3)) * 8);
    const u16* gK = k  + ((size_t)bh * 2048 + srow) * 64 + sb * 32 + swc;
    const u16* gV = vT + ((size_t)bh * 64 + srow) * 2048 + sb * 32 + swc;

    auto stage = [&](int it, int buf) {
        int j0 = g * 1024 + it * 64;
        if ((wq & 2) == 0) {
            u16* ldst = KsG + buf * 4096 + sb * 2048;
#pragma unroll
            for (int i = 0; i < 4; i++)
                gload16(gK + (size_t)(j0 + i * 16) * 64, ldst + i * 16 * 32);
        } else {
            u16* ldst = VsG + buf * 4096 + sb * 2048;
#pragma unroll
            for (int i = 0; i < 4; i++)
                gload16(gV + (size_t)(i * 16) * 2048 + j0, ldst + i * 16 * 32);
        }
    };

    f32x4 zero4 = {0.f, 0.f, 0.f, 0.f};
    f32x4 lacc[2] = {zero4, zero4};
    f32x4 oacc[2][4];
#pragma unroll
    for (int qh = 0; qh < 2; qh++)
#pragma unroll
        for (int dt = 0; dt < 4; dt++) oacc[qh][dt] = zero4;

    stage(0, 0);
    __syncthreads();   // buf0 ready (vmcnt drained at barrier)

    for (int it = 0; it < 16; ++it) {
        const int buf = it & 1;
        // prefetch next tile into buf^1; its last readers finished at the
        // previous end-of-iter barrier
        if (it < 15) stage(it + 1, buf ^ 1);

        const u16* Kt = KsG + buf * 4096;
        const u16* Vt = VsG + buf * 4096;

        // S^T = K Q'^T : rows j (4 frags of 16), col q = lcol
        f32x4 sacc[2][4];
#pragma unroll
        for (int qh = 0; qh < 2; qh++)
#pragma unroll
            for (int jt = 0; jt < 4; jt++) sacc[qh][jt] = zero4;
        __builtin_amdgcn_s_setprio(1);
#pragma unroll
        for (int jt = 0; jt < 4; jt++)
#pragma unroll
            for (int db = 0; db < 2; db++) {
                bf16x8 kf = ld_frag(Kt + db * 2048 + (jt * 16 + lcol) * 32 + rsw);
#pragma unroll
                for (int qh = 0; qh < 2; qh++)
                    sacc[qh][jt] = __builtin_amdgcn_mfma_f32_16x16x32_bf16(kf, qf[qh][db], sacc[qh][jt], 0, 0, 0);
            }
        __builtin_amdgcn_s_setprio(0);

        // fixed-max softmax: p = exp2(s); pack to bf16 pairs in-register
        // lane(g=lquad, c=lcol) holds P[j = jt*16 + 4g + r][q = c]
        unsigned dpk[2][4][2];
#pragma unroll
        for (int qh = 0; qh < 2; qh++) {
#pragma unroll
            for (int jt = 0; jt < 4; jt++) {
                f32x4 pe;
                pe[0] = __builtin_amdgcn_exp2f(sacc[qh][jt][0]);
                pe[1] = __builtin_amdgcn_exp2f(sacc[qh][jt][1]);
                pe[2] = __builtin_amdgcn_exp2f(sacc[qh][jt][2]);
                pe[3] = __builtin_amdgcn_exp2f(sacc[qh][jt][3]);
                lacc[qh] += pe;
                dpk[qh][jt][0] = pk_bf16(pe[0], pe[1]);
                dpk[qh][jt][1] = pk_bf16(pe[2], pe[3]);
            }
        }

        // in-register P transpose: PV B-operand needs P[j = kb*32 + 8g + e][q=c].
        // permlane32_swap then permlane16_swap redistributes the packed pairs
        // exactly (verified element-wise for all 16 quad/word slots).
        bf16x8 pf[2][2];
#pragma unroll
        for (int qh = 0; qh < 2; qh++) {
#pragma unroll
            for (int kb = 0; kb < 2; kb++) {
                unsigned Ax = dpk[qh][2 * kb][0],     Ay = dpk[qh][2 * kb][1];
                unsigned Bx = dpk[qh][2 * kb + 1][0], By = dpk[qh][2 * kb + 1][1];
                u32x4 w;
#if __has_builtin(__builtin_amdgcn_permlane32_swap) && __has_builtin(__builtin_amdgcn_permlane16_swap)
                {
                    auto s1 = __builtin_amdgcn_permlane32_swap(Ax, Bx, false, false);
                    auto s2 = __builtin_amdgcn_permlane16_swap(s1[0], s1[1], false, false);
                    w[0] = s2[0]; w[2] = s2[1];
                    auto s3 = __builtin_amdgcn_permlane32_swap(Ay, By, false, false);
                    auto s4 = __builtin_amdgcn_permlane16_swap(s3[0], s3[1], false, false);
                    w[1] = s4[0]; w[3] = s4[1];
                }
#else
                {
                    unsigned x1x = (lquad < 2) ? Bx : Ax;
                    unsigned x1y = (lquad < 2) ? By : Ay;
                    unsigned r1x = __shfl_xor(x1x, 32, 64);
                    unsigned r1y = __shfl_xor(x1y, 32, 64);
                    unsigned x2x = (lquad == 1) ? Ax : (lquad == 2) ? Bx : r1x;
                    unsigned x2y = (lquad == 1) ? Ay : (lquad == 2) ? By : r1y;
                    unsigned r2x = __shfl_xor(x2x, 16, 64);
                    unsigned r2y = __shfl_xor(x2y, 16, 64);
                    w[0] = (lquad == 0) ? Ax : (lquad == 2) ? r1x : r2x;
                    w[1] = (lquad == 0) ? Ay : (lquad == 2) ? r1y : r2y;
                    w[2] = (lquad == 1) ? r1x : (lquad == 3) ? Bx : r2x;
                    w[3] = (lquad == 1) ? r1y : (lquad == 3) ? By : r2y;
                }
#endif
                pf[qh][kb] = __builtin_bit_cast(bf16x8, w);
            }
        }

        // O^T += V^T P^T ; vf reused across q-halves
        __builtin_amdgcn_s_setprio(1);
#pragma unroll
        for (int dt = 0; dt < 4; dt++)
#pragma unroll
            for (int kb = 0; kb < 2; kb++) {
                bf16x8 vf = ld_frag(Vt + kb * 2048 + (dt * 16 + lcol) * 32 + rsw);
#pragma unroll
                for (int qh = 0; qh < 2; qh++)
                    oacc[qh][dt] = __builtin_amdgcn_mfma_f32_16x16x32_bf16(vf, pf[qh][kb], oacc[qh][dt], 0, 0, 0);
            }
        __builtin_amdgcn_s_setprio(0);

        // end-of-iter: drains prefetch vmcnt + all reads of buf before reuse
        __syncthreads();
    }

    // ---- cross-group combine: g1 writes partial (O, l); g0 sums ----
    // slot stride 44 floats (176B, 16B-aligned; banks spread 12*l mod 32)
    float* scr = (float*)smem;
    const int slot = wq * 64 + lane;
    if (g == 1) {
#pragma unroll
        for (int qh = 0; qh < 2; qh++) {
#pragma unroll
            for (int dt = 0; dt < 4; dt++)
                *(f32x4*)&scr[slot * 44 + qh * 16 + dt * 4] = oacc[qh][dt];
            *(f32x4*)&scr[slot * 44 + 32 + qh * 4] = lacc[qh];
        }
    }
    __syncthreads();
    if (g == 1) return;

#pragma unroll
    for (int qh = 0; qh < 2; qh++) {
#pragma unroll
        for (int dt = 0; dt < 4; dt++)
            oacc[qh][dt] += *(const f32x4*)&scr[slot * 44 + qh * 16 + dt * 4];
        lacc[qh] += *(const f32x4*)&scr[slot * 44 + 32 + qh * 4];
    }

    // epilogue: O^T[d][q]/l -> attnout[b, n=q, h*64+d]
    const int b = bh >> 4, h = bh & 15;
#pragma unroll
    for (int qh = 0; qh < 2; qh++) {
        float l = (lacc[qh][0] + lacc[qh][1]) + (lacc[qh][2] + lacc[qh][3]);
        l += __shfl_xor(l, 16, 64);
        l += __shfl_xor(l, 32, 64);
        float inv = 1.0f / l;
        const int n = row0 + qh * 16 + lcol;
        size_t base = ((size_t)b * 2048 + n) * 1024 + h * 64;
#pragma unroll
        for (int dt = 0; dt < 4; dt++) {
            uint2 o;
            o.x = pk_bf16(oacc[qh][dt][0] * inv, oacc[qh][dt][1] * inv);
            o.y = pk_bf16(oacc[qh][dt][2] * inv, oacc[qh][dt][3] * inv);
            *(uint2*)(attnout + base + dt * 16 + lquad * 4) = o;
        }
    }
}

extern "C" void kernel_launch(void* const* d_in, const int* in_sizes, int n_in,
                              void* d_out, int out_size, void* d_ws, size_t ws_size,
                              hipStream_t stream) {
    const float* x     = (const float*)d_in[0];
    const float* theta = (const float*)d_in[1];
    const float* Wg    = (const float*)d_in[2];
    const float* bg    = (const float*)d_in[3];
    const float* Wqkv  = (const float*)d_in[4];
    const float* bqkv  = (const float*)d_in[5];
    const float* Wproj = (const float*)d_in[6];
    const float* bproj = (const float*)d_in[7];
    float* out = (float*)d_out;

    unsigned char* ws = (unsigned char*)d_ws;
    const size_t MB = 1ull << 20;
    u16* x_bf     = (u16*)(ws + 0);
    u16* Wg_bf    = (u16*)(ws + 8 * MB);
    u16* Wqkv_bf  = (u16*)(ws + 10 * MB);
    u16* Wproj_bf = (u16*)(ws + 16 * MB);
    u16* xg_bf    = (u16*)(ws + 18 * MB);
    u16* q_bf     = (u16*)(ws + 26 * MB);
    u16* k_bf     = (u16*)(ws + 34 * MB);
    u16* vT_bf    = (u16*)(ws + 42 * MB);
    u16* ao_bf    = (u16*)(ws + 50 * MB);

    dim3 blk(256);
    cvt_all<<<9216, blk, 0, stream>>>(x, Wg, Wqkv, Wproj,
                                      x_bf, Wg_bf, Wqkv_bf, Wproj_bf);

    gemm64<<<dim3(64, 8), blk, 0, stream>>>(0, x_bf, Wg_bf, bg,
                                            x, theta, xg_bf, nullptr);
    gemm_bt<<<dim3(32, 24), blk, 0, stream>>>(xg_bf, Wqkv_bf, bqkv,
                                              q_bf, k_bf, vT_bf);
    attn_kernel<<<dim3(16, 32), dim3(512), 0, stream>>>(q_bf, k_bf, vT_bf, ao_bf);
    gemm64<<<dim3(64, 8), blk, 0, stream>>>(2, ao_bf, Wproj_bf, bproj,
                                            nullptr, nullptr, nullptr, out);
}

// Round 6
// 205.943 us; speedup vs baseline: 1.1948x; 1.0124x over previous
//
#include <hip/hip_runtime.h>
#include <stdint.h>

// ---- types ----
typedef __bf16 bf16x8 __attribute__((ext_vector_type(8)));
typedef __bf16 bf16x2 __attribute__((ext_vector_type(2)));
typedef float  f32x4  __attribute__((ext_vector_type(4)));
typedef unsigned int u32x4 __attribute__((ext_vector_type(4)));
typedef unsigned short u16;

// native RNE cast; compiler emits v_cvt_pk_bf16_f32 for pairs
__device__ __forceinline__ u16 f2bf(float f) {
    return __builtin_bit_cast(u16, (__bf16)f);
}

// packed 2x f32 -> bf16 (RNE); [15:0]=a, [31:16]=b
__device__ __forceinline__ unsigned pk_bf16(float a, float b) {
    bf16x2 r; r[0] = (__bf16)a; r[1] = (__bf16)b;
    return __builtin_bit_cast(unsigned, r);
}

__device__ __forceinline__ bf16x8 ld_frag(const u16* p) {
    u32x4 u = *(const u32x4*)p;
    return __builtin_bit_cast(bf16x8, u);
}

// async global->LDS, 16B per lane; LDS dest = wave-uniform base + lane*16
__device__ __forceinline__ void gload16(const u16* g, u16* l) {
    __builtin_amdgcn_global_load_lds(
        (__attribute__((address_space(1))) void*)g,
        (__attribute__((address_space(3))) void*)l,
        16, 0, 0);
}

#define ATT_CSC 0.18033688011112042f  // (1/sqrt(64)) * log2(e)

// ---- fused fp32 -> bf16 convert for all 4 arrays (float4-granular) ----
__global__ __launch_bounds__(256) void cvt_all(
    const float* __restrict__ x, const float* __restrict__ wg,
    const float* __restrict__ wqkv, const float* __restrict__ wproj,
    u16* __restrict__ xo, u16* __restrict__ wgo,
    u16* __restrict__ wqkvo, u16* __restrict__ wprojo)
{
    int i = blockIdx.x * 256 + threadIdx.x;   // grid covers exactly 2359296
    const float4* in; uint2* out; int off;
    if (i < 1048576)      { in = (const float4*)x;     out = (uint2*)xo;     off = i; }
    else if (i < 1310720) { in = (const float4*)wg;    out = (uint2*)wgo;    off = i - 1048576; }
    else if (i < 2097152) { in = (const float4*)wqkv;  out = (uint2*)wqkvo;  off = i - 1310720; }
    else                  { in = (const float4*)wproj; out = (uint2*)wprojo; off = i - 2097152; }
    float4 v = in[off];
    uint2 o; o.x = pk_bf16(v.x, v.y); o.y = pk_bf16(v.z, v.w);
    out[off] = o;
}

// ---- 128x128xBK64 bf16 MFMA GEMM (QKV), XOR-swizzled LDS ----
// BK=64: 16 k-iters (vs 32), halving barrier/drain count. LDS 32 KiB.
// rows are 64 u16 = 128 B = 8 chunks of 16 B; chunk swizzle:
// write phys chunk (lane&7), data chunk (lane&7)^(row&7);
// read logical chunk c=db*4+lquad at phys c^(row&7), row&7 == lcol&7.
__global__ __launch_bounds__(256) void gemm_bt(
    const u16* __restrict__ A,      // [4096,1024]
    const u16* __restrict__ W,      // [3072,1024]
    const float* __restrict__ bias,
    u16* __restrict__ qo, u16* __restrict__ ko, u16* __restrict__ vTo)
{
    __shared__ alignas(16) u16 As[128 * 64];
    __shared__ alignas(16) u16 Bs[128 * 64];
    const int tid  = threadIdx.x;
    const int wave = tid >> 6, lane = tid & 63;
    const int lquad = lane >> 4, lcol = lane & 15;
    const int wr = (wave >> 1) * 64, wc = (wave & 1) * 64;
    const int rowb = blockIdx.x * 128, colb = blockIdx.y * 128;
    const int srow8 = lane >> 3;                       // 0..7
    const int swc = (((lane & 7) ^ srow8) * 8);        // swizzled source chunk
    const int rs0 = ((0 * 4 + lquad) ^ (lcol & 7)) * 8;  // read chunk, db=0
    const int rs1 = ((1 * 4 + lquad) ^ (lcol & 7)) * 8;  // read chunk, db=1

    const u16* src  = (wave & 2) ? W : A;
    const int  rbase = (wave & 2) ? colb : rowb;
    u16* dst = ((wave & 2) ? Bs : As) + (wave & 1) * 64 * 64;
    const u16* gsrc = src + (size_t)(rbase + (wave & 1) * 64 + srow8) * 1024 + swc;

    f32x4 zero4 = {0.f, 0.f, 0.f, 0.f};
    f32x4 acc[4][4];
#pragma unroll
    for (int i = 0; i < 4; i++)
#pragma unroll
        for (int j = 0; j < 4; j++) acc[i][j] = zero4;

    for (int k0 = 0; k0 < 1024; k0 += 64) {
        __syncthreads();
#pragma unroll
        for (int i = 0; i < 8; i++)
            gload16(gsrc + (size_t)(i * 8) * 1024 + k0, dst + i * 8 * 64);
        __syncthreads();
#pragma unroll
        for (int db = 0; db < 2; db++) {
            const int rsw = db ? rs1 : rs0;
            bf16x8 af[4], bfr[4];
#pragma unroll
            for (int t = 0; t < 4; t++) af[t]  = ld_frag(As + (wr + t * 16 + lcol) * 64 + rsw);
#pragma unroll
            for (int t = 0; t < 4; t++) bfr[t] = ld_frag(Bs + (wc + t * 16 + lcol) * 64 + rsw);
#pragma unroll
            for (int i = 0; i < 4; i++)
#pragma unroll
                for (int j = 0; j < 4; j++)
                    acc[i][j] = __builtin_amdgcn_mfma_f32_16x16x32_bf16(af[i], bfr[j], acc[i][j], 0, 0, 0);
        }
    }

#pragma unroll
    for (int i = 0; i < 4; i++) {
#pragma unroll
        for (int j = 0; j < 4; j++) {
            int gcol = colb + wc + j * 16 + lcol;
            float bsv = bias[gcol];
            int grow0 = rowb + wr + i * 16 + lquad * 4;
            int three = gcol >> 10, rem = gcol & 1023;
            int h = rem >> 6, d = rem & 63;
            int b = grow0 >> 11, nn = grow0 & 2047;
            int bh = b * 16 + h;
            if (three == 2) {
                ushort4 o;
                o.x = f2bf(acc[i][j][0] + bsv);
                o.y = f2bf(acc[i][j][1] + bsv);
                o.z = f2bf(acc[i][j][2] + bsv);
                o.w = f2bf(acc[i][j][3] + bsv);
                *(ushort4*)(vTo + ((size_t)bh * 64 + d) * 2048 + nn) = o;
            } else if (three == 0) {
#pragma unroll
                for (int r = 0; r < 4; r++)
                    qo[((size_t)bh * 2048 + nn + r) * 64 + d] = f2bf((acc[i][j][r] + bsv) * ATT_CSC);
            } else {
#pragma unroll
                for (int r = 0; r < 4; r++)
                    ko[((size_t)bh * 2048 + nn + r) * 64 + d] = f2bf(acc[i][j][r] + bsv);
            }
        }
    }
}

// ---- 64x128xBK64 GEMM (gauge mode0 / proj mode2), grid (64, 8) = 512 blocks ----
__global__ __launch_bounds__(256) void gemm64(
    int mode,
    const u16* __restrict__ A,
    const u16* __restrict__ W,
    const float* __restrict__ bias,
    const float* __restrict__ xres,
    const float* __restrict__ theta,
    u16* __restrict__ out_bf,
    float* __restrict__ out_f)
{
    __shared__ alignas(16) u16 As[64 * 64];    // 8 KiB
    __shared__ alignas(16) u16 Bs[128 * 64];   // 16 KiB
    const int tid  = threadIdx.x;
    const int wave = tid >> 6, lane = tid & 63;
    const int lquad = lane >> 4, lcol = lane & 15;
    const int wr = (wave & 1) * 32, wc = (wave >> 1) * 64;
    const int rowb = blockIdx.x * 64, colb = blockIdx.y * 128;
    const int srow8 = lane >> 3;
    const int swc = (((lane & 7) ^ srow8) * 8);
    const int rs0 = ((0 * 4 + lquad) ^ (lcol & 7)) * 8;
    const int rs1 = ((1 * 4 + lquad) ^ (lcol & 7)) * 8;

    const u16* gp[3]; u16* lp[3];
#pragma unroll
    for (int t = 0; t < 3; t++) {
        int id = wave + t * 4;
        if (id < 4) {
            gp[t] = A + (size_t)(rowb + id * 16 + srow8) * 1024 + swc;
            lp[t] = As + id * 16 * 64;
        } else {
            int g = id - 4;
            gp[t] = W + (size_t)(colb + g * 16 + srow8) * 1024 + swc;
            lp[t] = Bs + g * 16 * 64;
        }
    }

    f32x4 zero4 = {0.f, 0.f, 0.f, 0.f};
    f32x4 acc[2][4];
#pragma unroll
    for (int i = 0; i < 2; i++)
#pragma unroll
        for (int j = 0; j < 4; j++) acc[i][j] = zero4;

    for (int k0 = 0; k0 < 1024; k0 += 64) {
        __syncthreads();
#pragma unroll
        for (int t = 0; t < 3; t++) {
            gload16(gp[t] + k0, lp[t]);
            gload16(gp[t] + (size_t)8 * 1024 + k0, lp[t] + 8 * 64);
        }
        __syncthreads();
#pragma unroll
        for (int db = 0; db < 2; db++) {
            const int rsw = db ? rs1 : rs0;
            bf16x8 af[2], bfr[4];
#pragma unroll
            for (int t = 0; t < 2; t++) af[t]  = ld_frag(As + (wr + t * 16 + lcol) * 64 + rsw);
#pragma unroll
            for (int t = 0; t < 4; t++) bfr[t] = ld_frag(Bs + (wc + t * 16 + lcol) * 64 + rsw);
#pragma unroll
            for (int i = 0; i < 2; i++)
#pragma unroll
                for (int j = 0; j < 4; j++)
                    acc[i][j] = __builtin_amdgcn_mfma_f32_16x16x32_bf16(af[i], bfr[j], acc[i][j], 0, 0, 0);
        }
    }

#pragma unroll
    for (int i = 0; i < 2; i++) {
#pragma unroll
        for (int j = 0; j < 4; j++) {
            int gcol = colb + wc + j * 16 + lcol;
            float bsv = bias[gcol];
            int grow0 = rowb + wr + i * 16 + lquad * 4;
            if (mode == 0) {
#pragma unroll
                for (int r = 0; r < 4; r++) {
                    size_t idx = (size_t)(grow0 + r) * 1024 + gcol;
                    float val = acc[i][j][r] + bsv;
                    out_bf[idx] = f2bf(xres[idx] + 0.1f * (val * theta[gcol]));
                }
            } else {
#pragma unroll
                for (int r = 0; r < 4; r++)
                    out_f[(size_t)(grow0 + r) * 1024 + gcol] = acc[i][j][r] + bsv;
            }
        }
    }
}

// ---- flash attention: split-j, 8 waves (2 j-groups x 4 q-waves) ----
// S^T = K Q'^T (q pre-scaled), P = exp2(S^T), O^T = V^T P^T
// Fixed-max softmax => pure linear accumulation over j: disjoint j-halves
// computed by separate wave groups, partial (O, l) summed at end.
// 4 waves/SIMD. j-tile 64, double-buffered: LDS 64 KiB. grid (16, 32).
__global__ __launch_bounds__(512, 4) void attn_kernel(
    const u16* __restrict__ q,   // [B*H, N, D] (pre-scaled by csc)
    const u16* __restrict__ k,   // [B*H, N, D]
    const u16* __restrict__ vT,  // [B*H, D, N]
    u16* __restrict__ attnout)   // [B, N, H*D]
{
    __shared__ alignas(16) u16 smem[32768];   // 64 KiB
    // Ks: smem          + g*8192 + buf*4096 + db*2048 : [db][j 64][32]
    // Vs: smem + 16384  + g*8192 + buf*4096 + jb*2048 : [jb][d 64][32]

    const int tid  = threadIdx.x;
    const int wave = tid >> 6, lane = tid & 63;
    const int g = wave >> 2, wq = wave & 3;
    const int lquad = lane >> 4, lcol = lane & 15;
    const int bh   = blockIdx.y;
    const int row0 = blockIdx.x * 128 + wq * 32;
    const int rsw  = (lquad ^ (lcol & 3)) * 8;

    u16* KsG = smem + g * 8192;
    u16* VsG = smem + 16384 + g * 8192;

    // Q as B-operand: n=lcol (q-row), k=d ; two q-halves of 16
    bf16x8 qf[2][2];
#pragma unroll
    for (int qh = 0; qh < 2; qh++)
#pragma unroll
        for (int db = 0; db < 2; db++)
            qf[qh][db] = ld_frag(q + ((size_t)bh * 2048 + row0 + qh * 16 + lcol) * 64 + db * 32 + lquad * 8);

    // staging roles within each group: wq 0,1 -> K (d-halves); wq 2,3 -> V^T (j-halves)
    const int sb = wq & 1;
    const int srow = lane >> 2;
    const int swc  = (((lane & 3) ^ (srow & 3)) * 8);
    const u16* gK = k  + ((size_t)bh * 2048 + srow) * 64 + sb * 32 + swc;
    const u16* gV = vT + ((size_t)bh * 64 + srow) * 2048 + sb * 32 + swc;

    auto stage = [&](int it, int buf) {
        int j0 = g * 1024 + it * 64;
        if ((wq & 2) == 0) {
            u16* ldst = KsG + buf * 4096 + sb * 2048;
#pragma unroll
            for (int i = 0; i < 4; i++)
                gload16(gK + (size_t)(j0 + i * 16) * 64, ldst + i * 16 * 32);
        } else {
            u16* ldst = VsG + buf * 4096 + sb * 2048;
#pragma unroll
            for (int i = 0; i < 4; i++)
                gload16(gV + (size_t)(i * 16) * 2048 + j0, ldst + i * 16 * 32);
        }
    };

    f32x4 zero4 = {0.f, 0.f, 0.f, 0.f};
    f32x4 lacc[2] = {zero4, zero4};
    f32x4 oacc[2][4];
#pragma unroll
    for (int qh = 0; qh < 2; qh++)
#pragma unroll
        for (int dt = 0; dt < 4; dt++) oacc[qh][dt] = zero4;

    stage(0, 0);
    __syncthreads();   // buf0 ready (vmcnt drained at barrier)

    for (int it = 0; it < 16; ++it) {
        const int buf = it & 1;
        // prefetch next tile into buf^1; its last readers finished at the
        // previous end-of-iter barrier
        if (it < 15) stage(it + 1, buf ^ 1);

        const u16* Kt = KsG + buf * 4096;
        const u16* Vt = VsG + buf * 4096;

        // S^T = K Q'^T : rows j (4 frags of 16), col q = lcol
        // db==0 uses zero4 as C directly: no per-iter sacc zero-init
        f32x4 sacc[2][4];
        __builtin_amdgcn_s_setprio(1);
#pragma unroll
        for (int jt = 0; jt < 4; jt++)
#pragma unroll
            for (int db = 0; db < 2; db++) {
                bf16x8 kf = ld_frag(Kt + db * 2048 + (jt * 16 + lcol) * 32 + rsw);
#pragma unroll
                for (int qh = 0; qh < 2; qh++)
                    sacc[qh][jt] = __builtin_amdgcn_mfma_f32_16x16x32_bf16(
                        kf, qf[qh][db], db == 0 ? zero4 : sacc[qh][jt], 0, 0, 0);
            }
        __builtin_amdgcn_s_setprio(0);

        // fixed-max softmax: p = exp2(s); pack to bf16 pairs in-register
        // lane(g=lquad, c=lcol) holds P[j = jt*16 + 4g + r][q = c]
        unsigned dpk[2][4][2];
#pragma unroll
        for (int qh = 0; qh < 2; qh++) {
#pragma unroll
            for (int jt = 0; jt < 4; jt++) {
                f32x4 pe;
                pe[0] = __builtin_amdgcn_exp2f(sacc[qh][jt][0]);
                pe[1] = __builtin_amdgcn_exp2f(sacc[qh][jt][1]);
                pe[2] = __builtin_amdgcn_exp2f(sacc[qh][jt][2]);
                pe[3] = __builtin_amdgcn_exp2f(sacc[qh][jt][3]);
                lacc[qh] += pe;
                dpk[qh][jt][0] = pk_bf16(pe[0], pe[1]);
                dpk[qh][jt][1] = pk_bf16(pe[2], pe[3]);
            }
        }

        // in-register P transpose: PV B-operand needs P[j = kb*32 + 8g + e][q=c].
        // permlane32_swap then permlane16_swap redistributes the packed pairs
        // exactly (verified element-wise for all 16 quad/word slots).
        bf16x8 pf[2][2];
#pragma unroll
        for (int qh = 0; qh < 2; qh++) {
#pragma unroll
            for (int kb = 0; kb < 2; kb++) {
                unsigned Ax = dpk[qh][2 * kb][0],     Ay = dpk[qh][2 * kb][1];
                unsigned Bx = dpk[qh][2 * kb + 1][0], By = dpk[qh][2 * kb + 1][1];
                u32x4 w;
#if __has_builtin(__builtin_amdgcn_permlane32_swap) && __has_builtin(__builtin_amdgcn_permlane16_swap)
                {
                    auto s1 = __builtin_amdgcn_permlane32_swap(Ax, Bx, false, false);
                    auto s2 = __builtin_amdgcn_permlane16_swap(s1[0], s1[1], false, false);
                    w[0] = s2[0]; w[2] = s2[1];
                    auto s3 = __builtin_amdgcn_permlane32_swap(Ay, By, false, false);
                    auto s4 = __builtin_amdgcn_permlane16_swap(s3[0], s3[1], false, false);
                    w[1] = s4[0]; w[3] = s4[1];
                }
#else
                {
                    unsigned x1x = (lquad < 2) ? Bx : Ax;
                    unsigned x1y = (lquad < 2) ? By : Ay;
                    unsigned r1x = __shfl_xor(x1x, 32, 64);
                    unsigned r1y = __shfl_xor(x1y, 32, 64);
                    unsigned x2x = (lquad == 1) ? Ax : (lquad == 2) ? Bx : r1x;
                    unsigned x2y = (lquad == 1) ? Ay : (lquad == 2) ? By : r1y;
                    unsigned r2x = __shfl_xor(x2x, 16, 64);
                    unsigned r2y = __shfl_xor(x2y, 16, 64);
                    w[0] = (lquad == 0) ? Ax : (lquad == 2) ? r1x : r2x;
                    w[1] = (lquad == 0) ? Ay : (lquad == 2) ? r1y : r2y;
                    w[2] = (lquad == 1) ? r1x : (lquad == 3) ? Bx : r2x;
                    w[3] = (lquad == 1) ? r1y : (lquad == 3) ? By : r2y;
                }
#endif
                pf[qh][kb] = __builtin_bit_cast(bf16x8, w);
            }
        }

        // O^T += V^T P^T ; vf reused across q-halves
        __builtin_amdgcn_s_setprio(1);
#pragma unroll
        for (int dt = 0; dt < 4; dt++)
#pragma unroll
            for (int kb = 0; kb < 2; kb++) {
                bf16x8 vf = ld_frag(Vt + kb * 2048 + (dt * 16 + lcol) * 32 + rsw);
#pragma unroll
                for (int qh = 0; qh < 2; qh++)
                    oacc[qh][dt] = __builtin_amdgcn_mfma_f32_16x16x32_bf16(vf, pf[qh][kb], oacc[qh][dt], 0, 0, 0);
            }
        __builtin_amdgcn_s_setprio(0);

        // end-of-iter: drains prefetch vmcnt + all reads of buf before reuse
        __syncthreads();
    }

    // ---- cross-group combine: g1 writes partial (O, l); g0 sums ----
    // slot stride 44 floats (176B, 16B-aligned; banks spread 12*l mod 32)
    float* scr = (float*)smem;
    const int slot = wq * 64 + lane;
    if (g == 1) {
#pragma unroll
        for (int qh = 0; qh < 2; qh++) {
#pragma unroll
            for (int dt = 0; dt < 4; dt++)
                *(f32x4*)&scr[slot * 44 + qh * 16 + dt * 4] = oacc[qh][dt];
            *(f32x4*)&scr[slot * 44 + 32 + qh * 4] = lacc[qh];
        }
    }
    __syncthreads();
    if (g == 1) return;

#pragma unroll
    for (int qh = 0; qh < 2; qh++) {
#pragma unroll
        for (int dt = 0; dt < 4; dt++)
            oacc[qh][dt] += *(const f32x4*)&scr[slot * 44 + qh * 16 + dt * 4];
        lacc[qh] += *(const f32x4*)&scr[slot * 44 + 32 + qh * 4];
    }

    // epilogue: O^T[d][q]/l -> attnout[b, n=q, h*64+d]
    const int b = bh >> 4, h = bh & 15;
#pragma unroll
    for (int qh = 0; qh < 2; qh++) {
        float l = (lacc[qh][0] + lacc[qh][1]) + (lacc[qh][2] + lacc[qh][3]);
        l += __shfl_xor(l, 16, 64);
        l += __shfl_xor(l, 32, 64);
        float inv = 1.0f / l;
        const int n = row0 + qh * 16 + lcol;
        size_t base = ((size_t)b * 2048 + n) * 1024 + h * 64;
#pragma unroll
        for (int dt = 0; dt < 4; dt++) {
            uint2 o;
            o.x = pk_bf16(oacc[qh][dt][0] * inv, oacc[qh][dt][1] * inv);
            o.y = pk_bf16(oacc[qh][dt][2] * inv, oacc[qh][dt][3] * inv);
            *(uint2*)(attnout + base + dt * 16 + lquad * 4) = o;
        }
    }
}

extern "C" void kernel_launch(void* const* d_in, const int* in_sizes, int n_in,
                              void* d_out, int out_size, void* d_ws, size_t ws_size,
                              hipStream_t stream) {
    const float* x     = (const float*)d_in[0];
    const float* theta = (const float*)d_in[1];
    const float* Wg    = (const float*)d_in[2];
    const float* bg    = (const float*)d_in[3];
    const float* Wqkv  = (const float*)d_in[4];
    const float* bqkv  = (const float*)d_in[5];
    const float* Wproj = (const float*)d_in[6];
    const float* bproj = (const float*)d_in[7];
    float* out = (float*)d_out;

    unsigned char* ws = (unsigned char*)d_ws;
    const size_t MB = 1ull << 20;
    u16* x_bf     = (u16*)(ws + 0);
    u16* Wg_bf    = (u16*)(ws + 8 * MB);
    u16* Wqkv_bf  = (u16*)(ws + 10 * MB);
    u16* Wproj_bf = (u16*)(ws + 16 * MB);
    u16* xg_bf    = (u16*)(ws + 18 * MB);
    u16* q_bf     = (u16*)(ws + 26 * MB);
    u16* k_bf     = (u16*)(ws + 34 * MB);
    u16* vT_bf    = (u16*)(ws + 42 * MB);
    u16* ao_bf    = (u16*)(ws + 50 * MB);

    dim3 blk(256);
    cvt_all<<<9216, blk, 0, stream>>>(x, Wg, Wqkv, Wproj,
                                      x_bf, Wg_bf, Wqkv_bf, Wproj_bf);

    gemm64<<<dim3(64, 8), blk, 0, stream>>>(0, x_bf, Wg_bf, bg,
                                            x, theta, xg_bf, nullptr);
    gemm_bt<<<dim3(32, 24), blk, 0, stream>>>(xg_bf, Wqkv_bf, bqkv,
                                              q_bf, k_bf, vT_bf);
    attn_kernel<<<dim3(16, 32), dim3(512), 0, stream>>>(q_bf, k_bf, vT_bf, ao_bf);
    gemm64<<<dim3(64, 8), blk, 0, stream>>>(2, ao_bf, Wproj_bf, bproj,
                                            nullptr, nullptr, nullptr, out);
}

// Round 7
// 191.241 us; speedup vs baseline: 1.2866x; 1.0769x over previous
//
#include <hip/hip_runtime.h>
#include <stdint.h>

// ---- types ----
typedef __bf16 bf16x8 __attribute__((ext_vector_type(8)));
typedef __bf16 bf16x2 __attribute__((ext_vector_type(2)));
typedef float  f32x4  __attribute__((ext_vector_type(4)));
typedef unsigned int u32x4 __attribute__((ext_vector_type(4)));
typedef unsigned short u16;

// native RNE cast; compiler emits v_cvt_pk_bf16_f32 for pairs
__device__ __forceinline__ u16 f2bf(float f) {
    return __builtin_bit_cast(u16, (__bf16)f);
}

// packed 2x f32 -> bf16 (RNE); [15:0]=a, [31:16]=b
__device__ __forceinline__ unsigned pk_bf16(float a, float b) {
    bf16x2 r; r[0] = (__bf16)a; r[1] = (__bf16)b;
    return __builtin_bit_cast(unsigned, r);
}

__device__ __forceinline__ bf16x8 ld_frag(const u16* p) {
    u32x4 u = *(const u32x4*)p;
    return __builtin_bit_cast(bf16x8, u);
}

// async global->LDS, 16B per lane; LDS dest = wave-uniform base + lane*16
__device__ __forceinline__ void gload16(const u16* g, u16* l) {
    __builtin_amdgcn_global_load_lds(
        (__attribute__((address_space(1))) void*)g,
        (__attribute__((address_space(3))) void*)l,
        16, 0, 0);
}

#define ATT_CSC 0.18033688011112042f  // (1/sqrt(64)) * log2(e)

// ---- fused fp32 -> bf16 convert for all 4 arrays (float4-granular) ----
__global__ __launch_bounds__(256) void cvt_all(
    const float* __restrict__ x, const float* __restrict__ wg,
    const float* __restrict__ wqkv, const float* __restrict__ wproj,
    u16* __restrict__ xo, u16* __restrict__ wgo,
    u16* __restrict__ wqkvo, u16* __restrict__ wprojo)
{
    int i = blockIdx.x * 256 + threadIdx.x;   // grid covers exactly 2359296
    const float4* in; uint2* out; int off;
    if (i < 1048576)      { in = (const float4*)x;     out = (uint2*)xo;     off = i; }
    else if (i < 1310720) { in = (const float4*)wg;    out = (uint2*)wgo;    off = i - 1048576; }
    else if (i < 2097152) { in = (const float4*)wqkv;  out = (uint2*)wqkvo;  off = i - 1310720; }
    else                  { in = (const float4*)wproj; out = (uint2*)wprojo; off = i - 2097152; }
    float4 v = in[off];
    uint2 o; o.x = pk_bf16(v.x, v.y); o.y = pk_bf16(v.z, v.w);
    out[off] = o;
}

// ---- 128x128xBK64 bf16 MFMA GEMM (QKV), 512 threads / 8 waves ----
// Grid (32,24)=768 blocks -> 3 blocks/CU x 8 waves = 6 waves/SIMD (was 3).
// Wave-grid 2(M)x4(N): each wave 64x32 out = acc[4][2].
// Staging: wave w stages rows [8w,8w+8) of each 64-row panel (4 gload16/thread).
// XOR chunk swizzle: phys chunk (lane&7) holds data chunk (lane&7)^(row&7).
__global__ __launch_bounds__(512, 6) void gemm_bt(
    const u16* __restrict__ A,      // [4096,1024]
    const u16* __restrict__ W,      // [3072,1024]
    const float* __restrict__ bias,
    u16* __restrict__ qo, u16* __restrict__ ko, u16* __restrict__ vTo)
{
    __shared__ alignas(16) u16 As[128 * 64];
    __shared__ alignas(16) u16 Bs[128 * 64];
    const int tid  = threadIdx.x;
    const int wave = tid >> 6, lane = tid & 63;
    const int lquad = lane >> 4, lcol = lane & 15;
    const int wr = (wave >> 2) * 64, wc = (wave & 3) * 32;
    const int rowb = blockIdx.x * 128, colb = blockIdx.y * 128;
    const int srow8 = lane >> 3;                         // 0..7
    const int swc = (((lane & 7) ^ srow8) * 8);          // swizzled source chunk
    const int rs0 = ((0 * 4 + lquad) ^ (lcol & 7)) * 8;  // read chunk, db=0
    const int rs1 = ((1 * 4 + lquad) ^ (lcol & 7)) * 8;  // read chunk, db=1

    const u16* gA = A + (size_t)(rowb + wave * 8 + srow8) * 1024 + swc;
    const u16* gB = W + (size_t)(colb + wave * 8 + srow8) * 1024 + swc;
    u16* dA = As + wave * 512;   // rows 8w..8w+7 (8 rows x 64 u16)
    u16* dB = Bs + wave * 512;

    f32x4 zero4 = {0.f, 0.f, 0.f, 0.f};
    f32x4 acc[4][2];
#pragma unroll
    for (int i = 0; i < 4; i++)
#pragma unroll
        for (int j = 0; j < 2; j++) acc[i][j] = zero4;

    for (int k0 = 0; k0 < 1024; k0 += 64) {
        __syncthreads();
        gload16(gA + k0, dA);
        gload16(gA + (size_t)64 * 1024 + k0, dA + 64 * 64);
        gload16(gB + k0, dB);
        gload16(gB + (size_t)64 * 1024 + k0, dB + 64 * 64);
        __syncthreads();
#pragma unroll
        for (int db = 0; db < 2; db++) {
            const int rsw = db ? rs1 : rs0;
            bf16x8 af[4], bfr[2];
#pragma unroll
            for (int t = 0; t < 4; t++) af[t]  = ld_frag(As + (wr + t * 16 + lcol) * 64 + rsw);
#pragma unroll
            for (int t = 0; t < 2; t++) bfr[t] = ld_frag(Bs + (wc + t * 16 + lcol) * 64 + rsw);
#pragma unroll
            for (int i = 0; i < 4; i++)
#pragma unroll
                for (int j = 0; j < 2; j++)
                    acc[i][j] = __builtin_amdgcn_mfma_f32_16x16x32_bf16(af[i], bfr[j], acc[i][j], 0, 0, 0);
        }
    }

#pragma unroll
    for (int i = 0; i < 4; i++) {
#pragma unroll
        for (int j = 0; j < 2; j++) {
            int gcol = colb + wc + j * 16 + lcol;
            float bsv = bias[gcol];
            int grow0 = rowb + wr + i * 16 + lquad * 4;
            int three = gcol >> 10, rem = gcol & 1023;
            int h = rem >> 6, d = rem & 63;
            int b = grow0 >> 11, nn = grow0 & 2047;
            int bh = b * 16 + h;
            if (three == 2) {
                ushort4 o;
                o.x = f2bf(acc[i][j][0] + bsv);
                o.y = f2bf(acc[i][j][1] + bsv);
                o.z = f2bf(acc[i][j][2] + bsv);
                o.w = f2bf(acc[i][j][3] + bsv);
                *(ushort4*)(vTo + ((size_t)bh * 64 + d) * 2048 + nn) = o;
            } else if (three == 0) {
#pragma unroll
                for (int r = 0; r < 4; r++)
                    qo[((size_t)bh * 2048 + nn + r) * 64 + d] = f2bf((acc[i][j][r] + bsv) * ATT_CSC);
            } else {
#pragma unroll
                for (int r = 0; r < 4; r++)
                    ko[((size_t)bh * 2048 + nn + r) * 64 + d] = f2bf(acc[i][j][r] + bsv);
            }
        }
    }
}

// ---- 64x128xBK64 GEMM (gauge mode0 / proj mode2), 512 threads / 8 waves ----
// Grid (64,8)=512 blocks -> 2 blocks/CU x 8 waves = 4 waves/SIMD (was 2).
// Wave-grid 2(M)x4(N): each wave 32x32 out = acc[2][2]. LDS 24 KiB.
__global__ __launch_bounds__(512, 4) void gemm64(
    int mode,
    const u16* __restrict__ A,
    const u16* __restrict__ W,
    const float* __restrict__ bias,
    const float* __restrict__ xres,
    const float* __restrict__ theta,
    u16* __restrict__ out_bf,
    float* __restrict__ out_f)
{
    __shared__ alignas(16) u16 As[64 * 64];    // 8 KiB
    __shared__ alignas(16) u16 Bs[128 * 64];   // 16 KiB
    const int tid  = threadIdx.x;
    const int wave = tid >> 6, lane = tid & 63;
    const int lquad = lane >> 4, lcol = lane & 15;
    const int wr = (wave & 1) * 32, wc = (wave >> 1) * 32;
    const int rowb = blockIdx.x * 64, colb = blockIdx.y * 128;
    const int srow8 = lane >> 3;
    const int swc = (((lane & 7) ^ srow8) * 8);
    const int rs0 = ((0 * 4 + lquad) ^ (lcol & 7)) * 8;
    const int rs1 = ((1 * 4 + lquad) ^ (lcol & 7)) * 8;

    const u16* gA = A + (size_t)(rowb + wave * 8 + srow8) * 1024 + swc;
    const u16* gB = W + (size_t)(colb + wave * 8 + srow8) * 1024 + swc;
    u16* dA = As + wave * 512;
    u16* dB = Bs + wave * 512;

    f32x4 zero4 = {0.f, 0.f, 0.f, 0.f};
    f32x4 acc[2][2];
#pragma unroll
    for (int i = 0; i < 2; i++)
#pragma unroll
        for (int j = 0; j < 2; j++) acc[i][j] = zero4;

    for (int k0 = 0; k0 < 1024; k0 += 64) {
        __syncthreads();
        gload16(gA + k0, dA);
        gload16(gB + k0, dB);
        gload16(gB + (size_t)64 * 1024 + k0, dB + 64 * 64);
        __syncthreads();
#pragma unroll
        for (int db = 0; db < 2; db++) {
            const int rsw = db ? rs1 : rs0;
            bf16x8 af[2], bfr[2];
#pragma unroll
            for (int t = 0; t < 2; t++) af[t]  = ld_frag(As + (wr + t * 16 + lcol) * 64 + rsw);
#pragma unroll
            for (int t = 0; t < 2; t++) bfr[t] = ld_frag(Bs + (wc + t * 16 + lcol) * 64 + rsw);
#pragma unroll
            for (int i = 0; i < 2; i++)
#pragma unroll
                for (int j = 0; j < 2; j++)
                    acc[i][j] = __builtin_amdgcn_mfma_f32_16x16x32_bf16(af[i], bfr[j], acc[i][j], 0, 0, 0);
        }
    }

#pragma unroll
    for (int i = 0; i < 2; i++) {
#pragma unroll
        for (int j = 0; j < 2; j++) {
            int gcol = colb + wc + j * 16 + lcol;
            float bsv = bias[gcol];
            int grow0 = rowb + wr + i * 16 + lquad * 4;
            if (mode == 0) {
#pragma unroll
                for (int r = 0; r < 4; r++) {
                    size_t idx = (size_t)(grow0 + r) * 1024 + gcol;
                    float val = acc[i][j][r] + bsv;
                    out_bf[idx] = f2bf(xres[idx] + 0.1f * (val * theta[gcol]));
                }
            } else {
#pragma unroll
                for (int r = 0; r < 4; r++)
                    out_f[(size_t)(grow0 + r) * 1024 + gcol] = acc[i][j][r] + bsv;
            }
        }
    }
}

// ---- flash attention: split-j, 8 waves (2 j-groups x 4 q-waves) ----
// S^T = K Q'^T (q pre-scaled), P = exp2(S^T), O^T = V^T P^T
// Fixed-max softmax => pure linear accumulation over j: disjoint j-halves
// computed by separate wave groups, partial (O, l) summed at end.
// 4 waves/SIMD. j-tile 64, double-buffered: LDS 64 KiB. grid (16, 32).
__global__ __launch_bounds__(512, 4) void attn_kernel(
    const u16* __restrict__ q,   // [B*H, N, D] (pre-scaled by csc)
    const u16* __restrict__ k,   // [B*H, N, D]
    const u16* __restrict__ vT,  // [B*H, D, N]
    u16* __restrict__ attnout)   // [B, N, H*D]
{
    __shared__ alignas(16) u16 smem[32768];   // 64 KiB
    // Ks: smem          + g*8192 + buf*4096 + db*2048 : [db][j 64][32]
    // Vs: smem + 16384  + g*8192 + buf*4096 + jb*2048 : [jb][d 64][32]

    const int tid  = threadIdx.x;
    const int wave = tid >> 6, lane = tid & 63;
    const int g = wave >> 2, wq = wave & 3;
    const int lquad = lane >> 4, lcol = lane & 15;
    const int bh   = blockIdx.y;
    const int row0 = blockIdx.x * 128 + wq * 32;
    const int rsw  = (lquad ^ (lcol & 3)) * 8;

    u16* KsG = smem + g * 8192;
    u16* VsG = smem + 16384 + g * 8192;

    // Q as B-operand: n=lcol (q-row), k=d ; two q-halves of 16
    bf16x8 qf[2][2];
#pragma unroll
    for (int qh = 0; qh < 2; qh++)
#pragma unroll
        for (int db = 0; db < 2; db++)
            qf[qh][db] = ld_frag(q + ((size_t)bh * 2048 + row0 + qh * 16 + lcol) * 64 + db * 32 + lquad * 8);

    // staging roles within each group: wq 0,1 -> K (d-halves); wq 2,3 -> V^T (j-halves)
    const int sb = wq & 1;
    const int srow = lane >> 2;
    const int swc  = (((lane & 3) ^ (srow & 3)) * 8);
    const u16* gK = k  + ((size_t)bh * 2048 + srow) * 64 + sb * 32 + swc;
    const u16* gV = vT + ((size_t)bh * 64 + srow) * 2048 + sb * 32 + swc;

    auto stage = [&](int it, int buf) {
        int j0 = g * 1024 + it * 64;
        if ((wq & 2) == 0) {
            u16* ldst = KsG + buf * 4096 + sb * 2048;
#pragma unroll
            for (int i = 0; i < 4; i++)
                gload16(gK + (size_t)(j0 + i * 16) * 64, ldst + i * 16 * 32);
        } else {
            u16* ldst = VsG + buf * 4096 + sb * 2048;
#pragma unroll
            for (int i = 0; i < 4; i++)
                gload16(gV + (size_t)(i * 16) * 2048 + j0, ldst + i * 16 * 32);
        }
    };

    f32x4 zero4 = {0.f, 0.f, 0.f, 0.f};
    f32x4 lacc[2] = {zero4, zero4};
    f32x4 oacc[2][4];
#pragma unroll
    for (int qh = 0; qh < 2; qh++)
#pragma unroll
        for (int dt = 0; dt < 4; dt++) oacc[qh][dt] = zero4;

    stage(0, 0);
    __syncthreads();   // buf0 ready (vmcnt drained at barrier)

    for (int it = 0; it < 16; ++it) {
        const int buf = it & 1;
        // prefetch next tile into buf^1; its last readers finished at the
        // previous end-of-iter barrier
        if (it < 15) stage(it + 1, buf ^ 1);

        const u16* Kt = KsG + buf * 4096;
        const u16* Vt = VsG + buf * 4096;

        // S^T = K Q'^T : rows j (4 frags of 16), col q = lcol
        // db==0 uses zero4 as C directly: no per-iter sacc zero-init
        f32x4 sacc[2][4];
        __builtin_amdgcn_s_setprio(1);
#pragma unroll
        for (int jt = 0; jt < 4; jt++)
#pragma unroll
            for (int db = 0; db < 2; db++) {
                bf16x8 kf = ld_frag(Kt + db * 2048 + (jt * 16 + lcol) * 32 + rsw);
#pragma unroll
                for (int qh = 0; qh < 2; qh++)
                    sacc[qh][jt] = __builtin_amdgcn_mfma_f32_16x16x32_bf16(
                        kf, qf[qh][db], db == 0 ? zero4 : sacc[qh][jt], 0, 0, 0);
            }
        __builtin_amdgcn_s_setprio(0);

        // fixed-max softmax: p = exp2(s); pack to bf16 pairs in-register
        // lane(g=lquad, c=lcol) holds P[j = jt*16 + 4g + r][q = c]
        unsigned dpk[2][4][2];
#pragma unroll
        for (int qh = 0; qh < 2; qh++) {
#pragma unroll
            for (int jt = 0; jt < 4; jt++) {
                f32x4 pe;
                pe[0] = __builtin_amdgcn_exp2f(sacc[qh][jt][0]);
                pe[1] = __builtin_amdgcn_exp2f(sacc[qh][jt][1]);
                pe[2] = __builtin_amdgcn_exp2f(sacc[qh][jt][2]);
                pe[3] = __builtin_amdgcn_exp2f(sacc[qh][jt][3]);
                lacc[qh] += pe;
                dpk[qh][jt][0] = pk_bf16(pe[0], pe[1]);
                dpk[qh][jt][1] = pk_bf16(pe[2], pe[3]);
            }
        }

        // in-register P transpose: PV B-operand needs P[j = kb*32 + 8g + e][q=c].
        // permlane32_swap then permlane16_swap redistributes the packed pairs
        // exactly (verified element-wise for all 16 quad/word slots).
        bf16x8 pf[2][2];
#pragma unroll
        for (int qh = 0; qh < 2; qh++) {
#pragma unroll
            for (int kb = 0; kb < 2; kb++) {
                unsigned Ax = dpk[qh][2 * kb][0],     Ay = dpk[qh][2 * kb][1];
                unsigned Bx = dpk[qh][2 * kb + 1][0], By = dpk[qh][2 * kb + 1][1];
                u32x4 w;
#if __has_builtin(__builtin_amdgcn_permlane32_swap) && __has_builtin(__builtin_amdgcn_permlane16_swap)
                {
                    auto s1 = __builtin_amdgcn_permlane32_swap(Ax, Bx, false, false);
                    auto s2 = __builtin_amdgcn_permlane16_swap(s1[0], s1[1], false, false);
                    w[0] = s2[0]; w[2] = s2[1];
                    auto s3 = __builtin_amdgcn_permlane32_swap(Ay, By, false, false);
                    auto s4 = __builtin_amdgcn_permlane16_swap(s3[0], s3[1], false, false);
                    w[1] = s4[0]; w[3] = s4[1];
                }
#else
                {
                    unsigned x1x = (lquad < 2) ? Bx : Ax;
                    unsigned x1y = (lquad < 2) ? By : Ay;
                    unsigned r1x = __shfl_xor(x1x, 32, 64);
                    unsigned r1y = __shfl_xor(x1y, 32, 64);
                    unsigned x2x = (lquad == 1) ? Ax : (lquad == 2) ? Bx : r1x;
                    unsigned x2y = (lquad == 1) ? Ay : (lquad == 2) ? By : r1y;
                    unsigned r2x = __shfl_xor(x2x, 16, 64);
                    unsigned r2y = __shfl_xor(x2y, 16, 64);
                    w[0] = (lquad == 0) ? Ax : (lquad == 2) ? r1x : r2x;
                    w[1] = (lquad == 0) ? Ay : (lquad == 2) ? r1y : r2y;
                    w[2] = (lquad == 1) ? r1x : (lquad == 3) ? Bx : r2x;
                    w[3] = (lquad == 1) ? r1y : (lquad == 3) ? By : r2y;
                }
#endif
                pf[qh][kb] = __builtin_bit_cast(bf16x8, w);
            }
        }

        // O^T += V^T P^T ; vf reused across q-halves
        __builtin_amdgcn_s_setprio(1);
#pragma unroll
        for (int dt = 0; dt < 4; dt++)
#pragma unroll
            for (int kb = 0; kb < 2; kb++) {
                bf16x8 vf = ld_frag(Vt + kb * 2048 + (dt * 16 + lcol) * 32 + rsw);
#pragma unroll
                for (int qh = 0; qh < 2; qh++)
                    oacc[qh][dt] = __builtin_amdgcn_mfma_f32_16x16x32_bf16(vf, pf[qh][kb], oacc[qh][dt], 0, 0, 0);
            }
        __builtin_amdgcn_s_setprio(0);

        // end-of-iter: drains prefetch vmcnt + all reads of buf before reuse
        __syncthreads();
    }

    // ---- cross-group combine: g1 writes partial (O, l); g0 sums ----
    // slot stride 44 floats (176B, 16B-aligned; banks spread 12*l mod 32)
    float* scr = (float*)smem;
    const int slot = wq * 64 + lane;
    if (g == 1) {
#pragma unroll
        for (int qh = 0; qh < 2; qh++) {
#pragma unroll
            for (int dt = 0; dt < 4; dt++)
                *(f32x4*)&scr[slot * 44 + qh * 16 + dt * 4] = oacc[qh][dt];
            *(f32x4*)&scr[slot * 44 + 32 + qh * 4] = lacc[qh];
        }
    }
    __syncthreads();
    if (g == 1) return;

#pragma unroll
    for (int qh = 0; qh < 2; qh++) {
#pragma unroll
        for (int dt = 0; dt < 4; dt++)
            oacc[qh][dt] += *(const f32x4*)&scr[slot * 44 + qh * 16 + dt * 4];
        lacc[qh] += *(const f32x4*)&scr[slot * 44 + 32 + qh * 4];
    }

    // epilogue: O^T[d][q]/l -> attnout[b, n=q, h*64+d]
    const int b = bh >> 4, h = bh & 15;
#pragma unroll
    for (int qh = 0; qh < 2; qh++) {
        float l = (lacc[qh][0] + lacc[qh][1]) + (lacc[qh][2] + lacc[qh][3]);
        l += __shfl_xor(l, 16, 64);
        l += __shfl_xor(l, 32, 64);
        float inv = 1.0f / l;
        const int n = row0 + qh * 16 + lcol;
        size_t base = ((size_t)b * 2048 + n) * 1024 + h * 64;
#pragma unroll
        for (int dt = 0; dt < 4; dt++) {
            uint2 o;
            o.x = pk_bf16(oacc[qh][dt][0] * inv, oacc[qh][dt][1] * inv);
            o.y = pk_bf16(oacc[qh][dt][2] * inv, oacc[qh][dt][3] * inv);
            *(uint2*)(attnout + base + dt * 16 + lquad * 4) = o;
        }
    }
}

extern "C" void kernel_launch(void* const* d_in, const int* in_sizes, int n_in,
                              void* d_out, int out_size, void* d_ws, size_t ws_size,
                              hipStream_t stream) {
    const float* x     = (const float*)d_in[0];
    const float* theta = (const float*)d_in[1];
    const float* Wg    = (const float*)d_in[2];
    const float* bg    = (const float*)d_in[3];
    const float* Wqkv  = (const float*)d_in[4];
    const float* bqkv  = (const float*)d_in[5];
    const float* Wproj = (const float*)d_in[6];
    const float* bproj = (const float*)d_in[7];
    float* out = (float*)d_out;

    unsigned char* ws = (unsigned char*)d_ws;
    const size_t MB = 1ull << 20;
    u16* x_bf     = (u16*)(ws + 0);
    u16* Wg_bf    = (u16*)(ws + 8 * MB);
    u16* Wqkv_bf  = (u16*)(ws + 10 * MB);
    u16* Wproj_bf = (u16*)(ws + 16 * MB);
    u16* xg_bf    = (u16*)(ws + 18 * MB);
    u16* q_bf     = (u16*)(ws + 26 * MB);
    u16* k_bf     = (u16*)(ws + 34 * MB);
    u16* vT_bf    = (u16*)(ws + 42 * MB);
    u16* ao_bf    = (u16*)(ws + 50 * MB);

    dim3 blk(256);
    cvt_all<<<9216, blk, 0, stream>>>(x, Wg, Wqkv, Wproj,
                                      x_bf, Wg_bf, Wqkv_bf, Wproj_bf);

    gemm64<<<dim3(64, 8), dim3(512), 0, stream>>>(0, x_bf, Wg_bf, bg,
                                                  x, theta, xg_bf, nullptr);
    gemm_bt<<<dim3(32, 24), dim3(512), 0, stream>>>(xg_bf, Wqkv_bf, bqkv,
                                                    q_bf, k_bf, vT_bf);
    attn_kernel<<<dim3(16, 32), dim3(512), 0, stream>>>(q_bf, k_bf, vT_bf, ao_bf);
    gemm64<<<dim3(64, 8), dim3(512), 0, stream>>>(2, ao_bf, Wproj_bf, bproj,
                                                  nullptr, nullptr, nullptr, out);
}